// Round 2
// baseline (4417.366 us; speedup 1.0000x reference)
//
#include <hip/hip_runtime.h>
#include <hip/hip_bf16.h>
#include <cstdint>

#define BB 8
#define MM 36
#define DD 512
#define TT 64
#define HWW 196
#define NN 7056   /* MM*HWW */
#define NPAIR 64  /* BB*BB */
#define G1c 4.0f
#define G2c 5.0f
#define G3c 10.0f

__device__ __forceinline__ float bflySum(float v) {
#pragma unroll
  for (int off = 32; off > 0; off >>= 1) v += __shfl_xor(v, off, 64);
  return v;
}
__device__ __forceinline__ float bflyMax(float v) {
#pragma unroll
  for (int off = 32; off > 0; off >>= 1) v = fmaxf(v, __shfl_xor(v, off, 64));
  return v;
}

// K0: image[b][m][d][hw] -> v_rows[(b*NN + m*HWW + hw)][d]  (row-major v)
__global__ void k0_transpose(const float* __restrict__ image,
                             float* __restrict__ v_rows) {
  __shared__ float tile[32][33];
  int bm = blockIdx.x;        // 0..287  (b*MM + m)
  int hw0 = blockIdx.y * 32;  // 7 tiles cover 196
  int d0 = blockIdx.z * 32;   // 16 tiles cover 512
  int tx = threadIdx.x;       // 0..31
  int ty = threadIdx.y;       // 0..7
  const float* src = image + ((size_t)bm * DD + d0) * HWW + hw0;
#pragma unroll
  for (int r = 0; r < 32; r += 8) {
    int d = r + ty;
    if (hw0 + tx < HWW) tile[d][tx] = src[(size_t)d * HWW + tx];
  }
  __syncthreads();
  float* dst = v_rows + ((size_t)bm * HWW + hw0) * DD + d0;
#pragma unroll
  for (int r = 0; r < 32; r += 8) {
    int hwo = r + ty;
    if (hw0 + hwo < HWW) dst[(size_t)hwo * DD + tx] = tile[tx][hwo];
  }
}

// K1: per (pair, m): sim column + softmax over t; store attnT (=exp(G1*ns),
// unnormalized, transposed), s[t][m] = sum_hw exp(ns), atomic A[t] = sum_n exp(G1*ns)
__global__ void __launch_bounds__(256) k1_phaseA(
    const float* __restrict__ image, const float* __restrict__ text,
    float* __restrict__ attnT, float* __restrict__ sbuf,
    float* __restrict__ Abuf) {
  int m = blockIdx.x;     // 0..35
  int pair = blockIdx.y;  // 0..63
  int i = pair >> 3, j = pair & 7;
  int tid = threadIdx.x;
  int lane = tid & 63, wid = tid >> 6;
  bool act = tid < HWW;
  int hw = act ? tid : (HWW - 1);
  const float* vimg = image + ((size_t)(i * MM + m) * DD) * HWW + hw;
  const float* e = text + (size_t)j * TT * DD;

  float acc[TT];
#pragma unroll
  for (int t = 0; t < TT; ++t) acc[t] = 0.f;

  for (int d0 = 0; d0 < DD; d0 += 16) {
    float vv[16];
#pragma unroll
    for (int k = 0; k < 16; ++k) vv[k] = vimg[(size_t)(d0 + k) * HWW];
#pragma unroll
    for (int t = 0; t < TT; ++t) {
#pragma unroll
      for (int k = 0; k < 16; ++k)
        acc[t] = fmaf(e[t * DD + d0 + k], vv[k], acc[t]);
    }
  }

  // softmax over t (axis 0)
  float mx = acc[0];
#pragma unroll
  for (int t = 1; t < TT; ++t) mx = fmaxf(mx, acc[t]);
  float z = 0.f;
#pragma unroll
  for (int t = 0; t < TT; ++t) { acc[t] = expf(acc[t] - mx); z += acc[t]; }
  float rz = 1.f / z;

  __shared__ float lds_w[4][TT];
  __shared__ float lds_a[4][TT];
  size_t stbase = ((size_t)pair * NN + (size_t)m * HWW + hw) * TT;
  float stv[4];
#pragma unroll
  for (int t = 0; t < TT; ++t) {
    float ns = acc[t] * rz;  // norm_sim in (0,1]
    float w = expf(ns);      // sim_exp
    float a2 = w * w;
    float a4 = a2 * a2;      // exp(G1*ns), G1 == 4
    stv[t & 3] = a4;
    if ((t & 3) == 3 && act)
      *(float4*)(attnT + stbase + (size_t)(t - 3)) =
          make_float4(stv[0], stv[1], stv[2], stv[3]);
    float wv = act ? w : 0.f;
    float av = act ? a4 : 0.f;
    float wsum = bflySum(wv);
    float asum = bflySum(av);
    if (lane == 0) { lds_w[wid][t] = wsum; lds_a[wid][t] = asum; }
  }
  __syncthreads();
  if (tid < TT) {
    int t = tid;
    float sw = lds_w[0][t] + lds_w[1][t] + lds_w[2][t] + lds_w[3][t];
    float sa = lds_a[0][t] + lds_a[1][t] + lds_a[2][t] + lds_a[3][t];
    sbuf[((size_t)pair * TT + t) * MM + m] = sw;
    atomicAdd(&Abuf[pair * TT + t], sa);
  }
}

// K2: v_tidal[t][d] = sum_n attnT[n][t]/A[t] * v_rows[n][d]
__global__ void __launch_bounds__(256) k2_phaseB(
    const float* __restrict__ attnT, const float* __restrict__ Abuf,
    const float* __restrict__ v_rows, float* __restrict__ v_tidal) {
  int pair = blockIdx.z;
  int i = pair >> 3;
  int lane = threadIdx.x & 63;  // = t
  int wid = threadIdx.x >> 6;
  int d0 = blockIdx.x * 128 + wid * 32;
  int n0 = blockIdx.y * (NN / 4);
  int n1 = n0 + (NN / 4);
  float rA = 1.f / Abuf[pair * TT + lane];
  float acc[32];
#pragma unroll
  for (int k = 0; k < 32; ++k) acc[k] = 0.f;
  const float* aT = attnT + (size_t)pair * NN * TT + lane;
  const float* vb = v_rows + (size_t)i * NN * DD + d0;
  for (int n = n0; n < n1; ++n) {
    float av = aT[(size_t)n * TT] * rA;
    const float* vr = vb + (size_t)n * DD;
#pragma unroll
    for (int k = 0; k < 32; ++k) acc[k] = fmaf(av, vr[k], acc[k]);
  }
  float* outp = v_tidal + ((size_t)pair * TT + lane) * DD + d0;
#pragma unroll
  for (int k = 0; k < 32; ++k) atomicAdd(&outp[k], acc[k]);
}

// K3: diag[t] = dot(v_tidal[t], e[t]); r_qd = (1/G2) log sum exp(G2*diag)
__global__ void __launch_bounds__(256) k3_rqd(
    const float* __restrict__ v_tidal, const float* __restrict__ text,
    float* __restrict__ r_qd) {
  int pair = blockIdx.x;
  int j = pair & 7;
  int lane = threadIdx.x & 63, wid = threadIdx.x >> 6;
  __shared__ float dg[TT];
  for (int tt = 0; tt < 16; ++tt) {
    int t = wid * 16 + tt;
    const float* vt = v_tidal + ((size_t)pair * TT + t) * DD;
    const float* e = text + ((size_t)j * TT + t) * DD;
    float a = 0.f;
#pragma unroll
    for (int k = 0; k < 8; ++k) {
      int d = k * 64 + lane;
      a = fmaf(vt[d], e[d], a);
    }
    a = bflySum(a);
    if (lane == 0) dg[t] = a;
  }
  __syncthreads();
  if (threadIdx.x < TT) {
    float v = dg[threadIdx.x] * G2c;
    float mxv = bflyMax(v);
    float zz = bflySum(expf(v - mxv));
    if (threadIdx.x == 0) r_qd[pair] = (mxv + logf(zz)) / G2c;
  }
}

// K4: beta[t][m] = s[t][m] / sum_t s[t][m]
__global__ void __launch_bounds__(256) k4_beta(const float* __restrict__ sbuf,
                                               float* __restrict__ beta) {
  int pair = blockIdx.x;
  __shared__ float sl[TT * MM];
  __shared__ float ls[MM];
  for (int idx = threadIdx.x; idx < TT * MM; idx += 256)
    sl[idx] = sbuf[(size_t)pair * TT * MM + idx];
  __syncthreads();
  if (threadIdx.x < MM) {
    float a = 0.f;
    for (int t = 0; t < TT; ++t) a += sl[t * MM + threadIdx.x];
    ls[threadIdx.x] = 1.f / a;
  }
  __syncthreads();
  for (int idx = threadIdx.x; idx < TT * MM; idx += 256) {
    int mcol = idx % MM;
    beta[(size_t)pair * TT * MM + idx] = sl[idx] * ls[mcol];
  }
}

// K5: e_prime[m][d] = sum_t e[t][d]*beta[t][m]; ep_norm[m] = ||e_prime[:,m]||
__global__ void __launch_bounds__(256) k5_eprime(
    const float* __restrict__ text, const float* __restrict__ beta,
    float* __restrict__ e_prime, float* __restrict__ ep_norm) {
  int m = blockIdx.x, pair = blockIdx.y;
  int j = pair & 7;
  int d = threadIdx.x * 2;
  float a0 = 0.f, a1 = 0.f;
  const float* bt = beta + (size_t)pair * TT * MM + m;
  const float* e = text + (size_t)j * TT * DD + d;
  for (int t = 0; t < TT; ++t) {
    float b = bt[t * MM];
    float2 ev = *(const float2*)(e + (size_t)t * DD);
    a0 = fmaf(ev.x, b, a0);
    a1 = fmaf(ev.y, b, a1);
  }
  *(float2*)(e_prime + ((size_t)pair * MM + m) * DD + d) = make_float2(a0, a1);
  __shared__ float buf[4];
  float nr = bflySum(a0 * a0 + a1 * a1);
  int lane = threadIdx.x & 63, wid = threadIdx.x >> 6;
  if (lane == 0) buf[wid] = nr;
  __syncthreads();
  if (threadIdx.x == 0)
    ep_norm[pair * MM + m] = sqrtf(buf[0] + buf[1] + buf[2] + buf[3]);
}

// K6: ref[m] = (1/HW) sum_hw dot(v[m,hw,:], ep[:,m]) / (||v[m,hw,:]|| * ||ep[:,m]||)
__global__ void __launch_bounds__(256) k6_ref(
    const float* __restrict__ image, const float* __restrict__ e_prime,
    const float* __restrict__ ep_norm, float* __restrict__ refb) {
  int m = blockIdx.x, pair = blockIdx.y;
  int i = pair >> 3;
  int tid = threadIdx.x;
  bool act = tid < HWW;
  int hw = act ? tid : (HWW - 1);
  const float* vimg = image + ((size_t)(i * MM + m) * DD) * HWW + hw;
  const float* ep = e_prime + ((size_t)pair * MM + m) * DD;
  float ve = 0.f, rn2 = 0.f;
  for (int d = 0; d < DD; d += 4) {
#pragma unroll
    for (int k = 0; k < 4; ++k) {
      float vv = vimg[(size_t)(d + k) * HWW];
      ve = fmaf(vv, ep[d + k], ve);
      rn2 = fmaf(vv, vv, rn2);
    }
  }
  float en = ep_norm[pair * MM + m];
  float val = act ? (ve / (sqrtf(rn2) * en)) : 0.f;
  val = bflySum(val);
  __shared__ float buf[4];
  int lane = tid & 63, wid = tid >> 6;
  if (lane == 0) buf[wid] = val;
  __syncthreads();
  if (tid == 0)
    refb[pair * MM + m] = (buf[0] + buf[1] + buf[2] + buf[3]) * (1.0f / HWW);
}

// K7: r_qd2 = (1/G2) log sum_m exp(ref[m]);  S = r_qd + r_qd2
__global__ void k7_S(const float* __restrict__ refb,
                     const float* __restrict__ r_qd, float* __restrict__ Sb) {
  int pair = threadIdx.x;
  if (pair >= NPAIR) return;
  const float* r = refb + pair * MM;
  float mx = -1e30f;
  for (int mi = 0; mi < MM; ++mi) mx = fmaxf(mx, r[mi]);
  float z = 0.f;
  for (int mi = 0; mi < MM; ++mi) z += expf(r[mi] - mx);
  Sb[pair] = r_qd[pair] + (mx + logf(z)) / G2c;
}

// K8: final scalar loss
__global__ void __launch_bounds__(256) k8_loss(
    const float* __restrict__ Sb, const float* __restrict__ beta,
    const int* __restrict__ spinds, float* __restrict__ out) {
  __shared__ float bb[TT * MM];
  __shared__ float buf[4];
  __shared__ float sreg;
  int tid = threadIdx.x;
  if (tid == 0) sreg = 0.f;
  __syncthreads();
  for (int b = 0; b < BB; ++b) {
    size_t base = (size_t)(b * BB + b) * TT * MM;  // diagonal pair
    for (int idx = tid; idx < TT * MM; idx += 256) bb[idx] = beta[base + idx];
    __syncthreads();
    float val = 0.f;
    for (int k = 0; k < 16; ++k) {
      int idx = tid + k * 256;
      int t = idx >> 6, s2 = idx & 63;
      if (t != s2) {
        float dot = 0.f;
        for (int mi = 0; mi < MM; ++mi)
          dot = fmaf(bb[t * MM + mi], bb[s2 * MM + mi], dot);
        val += dot * dot;
      }
    }
    val = bflySum(val);
    int lane = tid & 63, wid = tid >> 6;
    if (lane == 0) buf[wid] = val;
    __syncthreads();
    if (tid == 0) sreg += sqrtf(fmaxf(buf[0] + buf[1] + buf[2] + buf[3], 0.f));
    __syncthreads();
  }
  if (tid == 0) {
    float l1 = 0.f, l2 = 0.f;
    for (int i = 0; i < BB; ++i) {
      float num = G3c * expf(Sb[i * BB + i]);
      float pdq = 0.f, pqd = 0.f;
      for (int k = 0; k < 5; ++k) {
        int kk = spinds[i * 5 + k];
        pdq += G3c * expf(Sb[i * BB + kk]);
        pqd += G3c * expf(Sb[kk * BB + i]);
      }
      l1 += num / pdq;
      l2 += num / pqd;
    }
    out[0] = -(l1 / BB) - (l2 / BB) + sreg / (float)(BB * TT * MM);
  }
}

extern "C" void kernel_launch(void* const* d_in, const int* in_sizes, int n_in,
                              void* d_out, int out_size, void* d_ws,
                              size_t ws_size, hipStream_t stream) {
  const float* image = (const float*)d_in[0];
  const float* text = (const float*)d_in[1];
  const int* spinds = (const int*)d_in[3];
  float* out = (float*)d_out;

  float* ws = (float*)d_ws;
  size_t off = 0;
  float* attnT = ws + off;   off += (size_t)NPAIR * NN * TT;   // 28.9M
  float* v_rows = ws + off;  off += (size_t)BB * NN * DD;      // 28.9M
  float* Abuf = ws + off;    off += (size_t)NPAIR * TT;        // 4096
  float* v_tidal = ws + off; off += (size_t)NPAIR * TT * DD;   // 2.1M
  float* sbuf = ws + off;    off += (size_t)NPAIR * TT * MM;
  float* beta = ws + off;    off += (size_t)NPAIR * TT * MM;
  float* e_prime = ws + off; off += (size_t)NPAIR * MM * DD;
  float* ep_norm = ws + off; off += (size_t)NPAIR * MM;
  float* refb = ws + off;    off += (size_t)NPAIR * MM;
  float* r_qd = ws + off;    off += (size_t)NPAIR;
  float* Sb = ws + off;      off += (size_t)NPAIR;

  // zero A (atomic accum) and v_tidal (atomic accum) — adjacent in layout
  hipMemsetAsync(Abuf, 0,
                 (size_t)(NPAIR * TT + (size_t)NPAIR * TT * DD) * sizeof(float),
                 stream);

  k0_transpose<<<dim3(BB * MM, 7, 16), dim3(32, 8), 0, stream>>>(image, v_rows);
  k1_phaseA<<<dim3(MM, NPAIR), 256, 0, stream>>>(image, text, attnT, sbuf, Abuf);
  k2_phaseB<<<dim3(4, 4, NPAIR), 256, 0, stream>>>(attnT, Abuf, v_rows, v_tidal);
  k3_rqd<<<NPAIR, 256, 0, stream>>>(v_tidal, text, r_qd);
  k4_beta<<<NPAIR, 256, 0, stream>>>(sbuf, beta);
  k5_eprime<<<dim3(MM, NPAIR), 256, 0, stream>>>(text, beta, e_prime, ep_norm);
  k6_ref<<<dim3(MM, NPAIR), 256, 0, stream>>>(image, e_prime, ep_norm, refb);
  k7_S<<<1, 64, 0, stream>>>(refb, r_qd, Sb);
  k8_loss<<<1, 256, 0, stream>>>(Sb, beta, spinds, out);
}

// Round 3
// 2722.979 us; speedup vs baseline: 1.6223x; 1.6223x over previous
//
#include <hip/hip_runtime.h>
#include <hip/hip_bf16.h>
#include <cstdint>

#define BB 8
#define MM 36
#define DD 512
#define TT 64
#define HWW 196
#define NN 7056   /* MM*HWW */
#define NPAIR 64  /* BB*BB */
#define KCH 28    /* K2 n-chunk; 28 | 196 and 28*63 == 1764 == NN/4 */
#define G1c 4.0f
#define G2c 5.0f
#define G3c 10.0f

__device__ __forceinline__ float bflySum(float v) {
#pragma unroll
  for (int off = 32; off > 0; off >>= 1) v += __shfl_xor(v, off, 64);
  return v;
}
__device__ __forceinline__ float bflyMax(float v) {
#pragma unroll
  for (int off = 32; off > 0; off >>= 1) v = fmaxf(v, __shfl_xor(v, off, 64));
  return v;
}

// K1: per (m, pair): sim column (thread = hw) + softmax over t.
// e staged in LDS per 16-d chunk (broadcast b128 reads).
// attnT stored coalesced via LDS transpose. sbuf (w-sums) + Abuf (a4-sums).
__global__ void __launch_bounds__(256) k1_phaseA(
    const float* __restrict__ image, const float* __restrict__ text,
    float* __restrict__ attnT, float* __restrict__ sbuf,
    float* __restrict__ Abuf) {
  int m = blockIdx.x;     // 0..35
  int pair = blockIdx.y;  // 0..63
  int i = pair >> 3, j = pair & 7;
  int tid = threadIdx.x;
  int lane = tid & 63, wid = tid >> 6;
  bool act = tid < HWW;
  int hw = act ? tid : (HWW - 1);
  const float* vimg = image + ((size_t)(i * MM + m) * DD) * HWW + hw;
  const float* etx = text + (size_t)j * TT * DD;

  __shared__ float es[TT * 16];  // [t][k], 4KB
  __shared__ float tb[64][65];   // transpose buffer, 16.6KB
  __shared__ float lds_w[4][TT];
  __shared__ float lds_a[4][TT];

  float acc[TT];
#pragma unroll
  for (int t = 0; t < TT; ++t) acc[t] = 0.f;

  for (int d0 = 0; d0 < DD; d0 += 16) {
    __syncthreads();
#pragma unroll
    for (int u = 0; u < 4; ++u) {
      int idx = tid + u * 256;  // 0..1023
      es[idx] = etx[(size_t)(idx >> 4) * DD + d0 + (idx & 15)];
    }
    __syncthreads();
    float vv[16];
#pragma unroll
    for (int k = 0; k < 16; ++k) vv[k] = vimg[(size_t)(d0 + k) * HWW];
#pragma unroll
    for (int t = 0; t < TT; ++t) {
      const float4 e0 = *(const float4*)&es[t * 16];
      const float4 e1 = *(const float4*)&es[t * 16 + 4];
      const float4 e2 = *(const float4*)&es[t * 16 + 8];
      const float4 e3 = *(const float4*)&es[t * 16 + 12];
      acc[t] = fmaf(e0.x, vv[0], acc[t]);
      acc[t] = fmaf(e0.y, vv[1], acc[t]);
      acc[t] = fmaf(e0.z, vv[2], acc[t]);
      acc[t] = fmaf(e0.w, vv[3], acc[t]);
      acc[t] = fmaf(e1.x, vv[4], acc[t]);
      acc[t] = fmaf(e1.y, vv[5], acc[t]);
      acc[t] = fmaf(e1.z, vv[6], acc[t]);
      acc[t] = fmaf(e1.w, vv[7], acc[t]);
      acc[t] = fmaf(e2.x, vv[8], acc[t]);
      acc[t] = fmaf(e2.y, vv[9], acc[t]);
      acc[t] = fmaf(e2.z, vv[10], acc[t]);
      acc[t] = fmaf(e2.w, vv[11], acc[t]);
      acc[t] = fmaf(e3.x, vv[12], acc[t]);
      acc[t] = fmaf(e3.y, vv[13], acc[t]);
      acc[t] = fmaf(e3.z, vv[14], acc[t]);
      acc[t] = fmaf(e3.w, vv[15], acc[t]);
    }
  }

  // softmax over t (axis 0)
  float mx = acc[0];
#pragma unroll
  for (int t = 1; t < TT; ++t) mx = fmaxf(mx, acc[t]);
  float z = 0.f;
#pragma unroll
  for (int t = 0; t < TT; ++t) { acc[t] = expf(acc[t] - mx); z += acc[t]; }
  float rz = 1.f / z;

  // w = exp(ns); a4 = exp(G1*ns) = w^4 (G1 == 4). acc[t] <- a4.
#pragma unroll
  for (int t = 0; t < TT; ++t) {
    float ns = acc[t] * rz;
    float w = expf(ns);
    float a2 = w * w;
    float a4 = a2 * a2;
    acc[t] = a4;
    float wsum = bflySum(act ? w : 0.f);
    float asum = bflySum(act ? a4 : 0.f);
    if (lane == 0) { lds_w[wid][t] = wsum; lds_a[wid][t] = asum; }
  }
  __syncthreads();
  if (tid < TT) {
    int t = tid;
    float sw = lds_w[0][t] + lds_w[1][t] + lds_w[2][t] + lds_w[3][t];
    float sa = lds_a[0][t] + lds_a[1][t] + lds_a[2][t] + lds_a[3][t];
    sbuf[((size_t)pair * TT + t) * MM + m] = sw;
    atomicAdd(&Abuf[pair * TT + t], sa);
  }

  // transposed, coalesced store of a4 into attnT[pair][n][t]
  for (int c = 0; c < 4; ++c) {
    __syncthreads();
    if (act && (tid >> 6) == c) {
#pragma unroll
      for (int t = 0; t < TT; ++t) tb[tid & 63][t] = acc[t];
    }
    __syncthreads();
    int rows = (c < 3) ? 64 : (HWW - 192);  // 64,64,64,4
    for (int fi = tid; fi < rows * 16; fi += 256) {
      int row = fi >> 4, tq = (fi & 15) * 4;
      float4 v4 = make_float4(tb[row][tq], tb[row][tq + 1], tb[row][tq + 2],
                              tb[row][tq + 3]);
      *(float4*)&attnT[((size_t)pair * NN + (size_t)m * HWW + c * 64 + row) * TT +
                       tq] = v4;
    }
  }
}

// K2: tiled fp32 GEMM. vt_part[s][pair][t][d] = sum_{n in chunk s} a4[n][t]*v[n][d]
// v staged straight from image with in-LDS transpose (chunk never crosses a box).
__global__ void __launch_bounds__(256) k2_gemm(
    const float* __restrict__ attnT, const float* __restrict__ image,
    float* __restrict__ vt_part) {
  int pair = blockIdx.z, i = pair >> 3;
  int d0 = blockIdx.x * 128;
  int nbase = blockIdx.y * (NN / 4);  // 1764
  int tid = threadIdx.x;
  int t0 = (tid & 15) * 4;
  int dl = (tid >> 4) * 8;
  __shared__ float as_[KCH][64];   // 7.2KB
  __shared__ float vs_[KCH][132];  // 14.8KB (pad 132 keeps b128 aligned)
  float acc[4][8];
#pragma unroll
  for (int q = 0; q < 4; ++q)
#pragma unroll
    for (int p = 0; p < 8; ++p) acc[q][p] = 0.f;

  for (int nc = 0; nc < 63; ++nc) {
    int n0 = nbase + nc * KCH;
    int mi = n0 / HWW;
    int hw0 = n0 - mi * HWW;  // multiple of 28
    __syncthreads();
    const float* ap = attnT + ((size_t)pair * NN + n0) * TT;
#pragma unroll
    for (int u = 0; u < 7; ++u) ((float*)as_)[tid + u * 256] = ap[tid + u * 256];
    const float* ip = image + ((size_t)(i * MM + mi) * DD + d0) * HWW + hw0;
#pragma unroll
    for (int u = 0; u < 14; ++u) {
      int idx = tid + u * 256;  // 0..3583
      int c = idx / KCH;
      int n = idx - c * KCH;
      vs_[n][c] = ip[(size_t)c * HWW + n];
    }
    __syncthreads();
#pragma unroll
    for (int n = 0; n < KCH; ++n) {
      float a[4], b[8];
      *(float4*)a = *(const float4*)&as_[n][t0];
      *(float4*)b = *(const float4*)&vs_[n][dl];
      *(float4*)(b + 4) = *(const float4*)&vs_[n][dl + 4];
#pragma unroll
      for (int q = 0; q < 4; ++q)
#pragma unroll
        for (int p = 0; p < 8; ++p) acc[q][p] = fmaf(a[q], b[p], acc[q][p]);
    }
  }
  float* op = vt_part +
              (((size_t)blockIdx.y * NPAIR + pair) * TT + t0) * DD + d0 + dl;
#pragma unroll
  for (int q = 0; q < 4; ++q) {
    *(float4*)&op[(size_t)q * DD] =
        make_float4(acc[q][0], acc[q][1], acc[q][2], acc[q][3]);
    *(float4*)&op[(size_t)q * DD + 4] =
        make_float4(acc[q][4], acc[q][5], acc[q][6], acc[q][7]);
  }
}

// K2b: v_tidal = (sum_s vt_part[s]) / A
__global__ void __launch_bounds__(256) k2b_reduce(
    const float* __restrict__ vt_part, const float* __restrict__ Abuf,
    float* __restrict__ v_tidal) {
  size_t f = (size_t)blockIdx.x * 256 + threadIdx.x;  // float4 index
  size_t base = f * 4;
  const size_t slab = (size_t)NPAIR * TT * DD;
  float rA = 1.f / Abuf[base >> 9];  // 512 floats per (pair,t) row
  float4 s0 = *(const float4*)&vt_part[base];
  float4 s1 = *(const float4*)&vt_part[slab + base];
  float4 s2 = *(const float4*)&vt_part[2 * slab + base];
  float4 s3 = *(const float4*)&vt_part[3 * slab + base];
  float4 r;
  r.x = (s0.x + s1.x + s2.x + s3.x) * rA;
  r.y = (s0.y + s1.y + s2.y + s3.y) * rA;
  r.z = (s0.z + s1.z + s2.z + s3.z) * rA;
  r.w = (s0.w + s1.w + s2.w + s3.w) * rA;
  *(float4*)&v_tidal[base] = r;
}

// K3: diag[t] = dot(v_tidal[t], e[t]); r_qd = (1/G2) log sum exp(G2*diag)
__global__ void __launch_bounds__(256) k3_rqd(
    const float* __restrict__ v_tidal, const float* __restrict__ text,
    float* __restrict__ r_qd) {
  int pair = blockIdx.x;
  int j = pair & 7;
  int lane = threadIdx.x & 63, wid = threadIdx.x >> 6;
  __shared__ float dg[TT];
  for (int tt = 0; tt < 16; ++tt) {
    int t = wid * 16 + tt;
    const float* vt = v_tidal + ((size_t)pair * TT + t) * DD;
    const float* e = text + ((size_t)j * TT + t) * DD;
    float a = 0.f;
#pragma unroll
    for (int k = 0; k < 8; ++k) {
      int d = k * 64 + lane;
      a = fmaf(vt[d], e[d], a);
    }
    a = bflySum(a);
    if (lane == 0) dg[t] = a;
  }
  __syncthreads();
  if (threadIdx.x < TT) {
    float v = dg[threadIdx.x] * G2c;
    float mxv = bflyMax(v);
    float zz = bflySum(expf(v - mxv));
    if (threadIdx.x == 0) r_qd[pair] = (mxv + logf(zz)) / G2c;
  }
}

// K4: beta[t][m] = s[t][m] / sum_t s[t][m]
__global__ void __launch_bounds__(256) k4_beta(const float* __restrict__ sbuf,
                                               float* __restrict__ beta) {
  int pair = blockIdx.x;
  __shared__ float sl[TT * MM];
  __shared__ float ls[MM];
  for (int idx = threadIdx.x; idx < TT * MM; idx += 256)
    sl[idx] = sbuf[(size_t)pair * TT * MM + idx];
  __syncthreads();
  if (threadIdx.x < MM) {
    float a = 0.f;
    for (int t = 0; t < TT; ++t) a += sl[t * MM + threadIdx.x];
    ls[threadIdx.x] = 1.f / a;
  }
  __syncthreads();
  for (int idx = threadIdx.x; idx < TT * MM; idx += 256) {
    int mcol = idx % MM;
    beta[(size_t)pair * TT * MM + idx] = sl[idx] * ls[mcol];
  }
}

// K5: e_prime[m][d] = sum_t e[t][d]*beta[t][m]; ep_norm[m] = ||e_prime[:,m]||
__global__ void __launch_bounds__(256) k5_eprime(
    const float* __restrict__ text, const float* __restrict__ beta,
    float* __restrict__ e_prime, float* __restrict__ ep_norm) {
  int m = blockIdx.x, pair = blockIdx.y;
  int j = pair & 7;
  int d = threadIdx.x * 2;
  float a0 = 0.f, a1 = 0.f;
  const float* bt = beta + (size_t)pair * TT * MM + m;
  const float* e = text + (size_t)j * TT * DD + d;
  for (int t = 0; t < TT; ++t) {
    float b = bt[t * MM];
    float2 ev = *(const float2*)(e + (size_t)t * DD);
    a0 = fmaf(ev.x, b, a0);
    a1 = fmaf(ev.y, b, a1);
  }
  *(float2*)(e_prime + ((size_t)pair * MM + m) * DD + d) = make_float2(a0, a1);
  __shared__ float buf[4];
  float nr = bflySum(a0 * a0 + a1 * a1);
  int lane = threadIdx.x & 63, wid = threadIdx.x >> 6;
  if (lane == 0) buf[wid] = nr;
  __syncthreads();
  if (threadIdx.x == 0)
    ep_norm[pair * MM + m] = sqrtf(buf[0] + buf[1] + buf[2] + buf[3]);
}

// K6: ref[m] = (1/HW) sum_hw dot(v[m,hw,:], ep[:,m]) / (||v[m,hw,:]|| * ||ep[:,m]||)
__global__ void __launch_bounds__(256) k6_ref(
    const float* __restrict__ image, const float* __restrict__ e_prime,
    const float* __restrict__ ep_norm, float* __restrict__ refb) {
  int m = blockIdx.x, pair = blockIdx.y;
  int i = pair >> 3;
  int tid = threadIdx.x;
  bool act = tid < HWW;
  int hw = act ? tid : (HWW - 1);
  const float* vimg = image + ((size_t)(i * MM + m) * DD) * HWW + hw;
  const float* ep = e_prime + ((size_t)pair * MM + m) * DD;
  float ve = 0.f, rn2 = 0.f;
  for (int d = 0; d < DD; d += 4) {
#pragma unroll
    for (int k = 0; k < 4; ++k) {
      float vv = vimg[(size_t)(d + k) * HWW];
      ve = fmaf(vv, ep[d + k], ve);
      rn2 = fmaf(vv, vv, rn2);
    }
  }
  float en = ep_norm[pair * MM + m];
  float val = act ? (ve / (sqrtf(rn2) * en)) : 0.f;
  val = bflySum(val);
  __shared__ float buf[4];
  int lane = tid & 63, wid = tid >> 6;
  if (lane == 0) buf[wid] = val;
  __syncthreads();
  if (tid == 0)
    refb[pair * MM + m] = (buf[0] + buf[1] + buf[2] + buf[3]) * (1.0f / HWW);
}

// K7: r_qd2 = (1/G2) log sum_m exp(ref[m]);  S = r_qd + r_qd2
__global__ void k7_S(const float* __restrict__ refb,
                     const float* __restrict__ r_qd, float* __restrict__ Sb) {
  int pair = threadIdx.x;
  if (pair >= NPAIR) return;
  const float* r = refb + pair * MM;
  float mx = -1e30f;
  for (int mi = 0; mi < MM; ++mi) mx = fmaxf(mx, r[mi]);
  float z = 0.f;
  for (int mi = 0; mi < MM; ++mi) z += expf(r[mi] - mx);
  Sb[pair] = r_qd[pair] + (mx + logf(z)) / G2c;
}

// K8: final scalar loss
__global__ void __launch_bounds__(256) k8_loss(
    const float* __restrict__ Sb, const float* __restrict__ beta,
    const int* __restrict__ spinds, float* __restrict__ out) {
  __shared__ float bb[TT * MM];
  __shared__ float buf[4];
  __shared__ float sreg;
  int tid = threadIdx.x;
  if (tid == 0) sreg = 0.f;
  __syncthreads();
  for (int b = 0; b < BB; ++b) {
    size_t base = (size_t)(b * BB + b) * TT * MM;
    for (int idx = tid; idx < TT * MM; idx += 256) bb[idx] = beta[base + idx];
    __syncthreads();
    float val = 0.f;
    for (int k = 0; k < 16; ++k) {
      int idx = tid + k * 256;
      int t = idx >> 6, s2 = idx & 63;
      if (t != s2) {
        float dot = 0.f;
        for (int mi = 0; mi < MM; ++mi)
          dot = fmaf(bb[t * MM + mi], bb[s2 * MM + mi], dot);
        val += dot * dot;
      }
    }
    val = bflySum(val);
    int lane = tid & 63, wid = tid >> 6;
    if (lane == 0) buf[wid] = val;
    __syncthreads();
    if (tid == 0) sreg += sqrtf(fmaxf(buf[0] + buf[1] + buf[2] + buf[3], 0.f));
    __syncthreads();
  }
  if (tid == 0) {
    float l1 = 0.f, l2 = 0.f;
    for (int i = 0; i < BB; ++i) {
      float num = G3c * expf(Sb[i * BB + i]);
      float pdq = 0.f, pqd = 0.f;
      for (int k = 0; k < 5; ++k) {
        int kk = spinds[i * 5 + k];
        pdq += G3c * expf(Sb[i * BB + kk]);
        pqd += G3c * expf(Sb[kk * BB + i]);
      }
      l1 += num / pdq;
      l2 += num / pqd;
    }
    out[0] = -(l1 / BB) - (l2 / BB) + sreg / (float)(BB * TT * MM);
  }
}

extern "C" void kernel_launch(void* const* d_in, const int* in_sizes, int n_in,
                              void* d_out, int out_size, void* d_ws,
                              size_t ws_size, hipStream_t stream) {
  const float* image = (const float*)d_in[0];
  const float* text = (const float*)d_in[1];
  const int* spinds = (const int*)d_in[3];
  float* out = (float*)d_out;

  float* ws = (float*)d_ws;
  size_t off = 0;
  float* attnT = ws + off;   off += (size_t)NPAIR * NN * TT;       // 28.9M
  float* vt_part = ws + off; off += (size_t)4 * NPAIR * TT * DD;   // 8.4M
  float* Abuf = ws + off;    off += (size_t)NPAIR * TT;
  float* v_tidal = ws + off; off += (size_t)NPAIR * TT * DD;
  float* sbuf = ws + off;    off += (size_t)NPAIR * TT * MM;
  float* beta = ws + off;    off += (size_t)NPAIR * TT * MM;
  float* e_prime = ws + off; off += (size_t)NPAIR * MM * DD;
  float* ep_norm = ws + off; off += (size_t)NPAIR * MM;
  float* refb = ws + off;    off += (size_t)NPAIR * MM;
  float* r_qd = ws + off;    off += (size_t)NPAIR;
  float* Sb = ws + off;      off += (size_t)NPAIR;

  hipMemsetAsync(Abuf, 0, (size_t)NPAIR * TT * sizeof(float), stream);

  k1_phaseA<<<dim3(MM, NPAIR), 256, 0, stream>>>(image, text, attnT, sbuf, Abuf);
  k2_gemm<<<dim3(4, 4, NPAIR), 256, 0, stream>>>(attnT, image, vt_part);
  k2b_reduce<<<2048, 256, 0, stream>>>(vt_part, Abuf, v_tidal);
  k3_rqd<<<NPAIR, 256, 0, stream>>>(v_tidal, text, r_qd);
  k4_beta<<<NPAIR, 256, 0, stream>>>(sbuf, beta);
  k5_eprime<<<dim3(MM, NPAIR), 256, 0, stream>>>(text, beta, e_prime, ep_norm);
  k6_ref<<<dim3(MM, NPAIR), 256, 0, stream>>>(image, e_prime, ep_norm, refb);
  k7_S<<<1, 64, 0, stream>>>(refb, r_qd, Sb);
  k8_loss<<<1, 256, 0, stream>>>(Sb, beta, spinds, out);
}

// Round 5
// 1273.910 us; speedup vs baseline: 3.4676x; 2.1375x over previous
//
#include <hip/hip_runtime.h>
#include <hip/hip_bf16.h>
#include <cstdint>

#define BB 8
#define MM 36
#define DD 512
#define TT 64
#define HWW 196
#define HWP 224   /* hw padded to 14*16 */
#define NN 7056
#define NNP 8064  /* MM*HWP */
#define NPAIR 64
#define G2c 5.0f
#define G3c 10.0f

typedef __attribute__((ext_vector_type(8))) short s8v;
typedef __attribute__((ext_vector_type(4))) float f4v;

__device__ __forceinline__ float bflySum(float v) {
#pragma unroll
  for (int off = 32; off > 0; off >>= 1) v += __shfl_xor(v, off, 64);
  return v;
}
__device__ __forceinline__ float bflyMax(float v) {
#pragma unroll
  for (int off = 32; off > 0; off >>= 1) v = fmaxf(v, __shfl_xor(v, off, 64));
  return v;
}
__device__ __forceinline__ unsigned short f2bf(float x) {
  __hip_bfloat16 h = __float2bfloat16(x);
  return *(unsigned short*)&h;
}

// P_text: text f32 -> eb bf16 (flat 262144)
__global__ void p_text(const float* __restrict__ text,
                       unsigned short* __restrict__ eb) {
  int idx = blockIdx.x * 256 + threadIdx.x;
  eb[idx] = f2bf(text[idx]);
}

// P_img: image[bm][d][196] f32 -> imgbp[bm][d][224] bf16 (pad zeros)
__global__ void __launch_bounds__(256) p_img(const float* __restrict__ image,
                                             unsigned int* __restrict__ imgbp) {
  int bm = blockIdx.x, ds = blockIdx.y;
  int tid = threadIdx.x;
  const float* src = image + ((size_t)bm * DD + ds * 32) * HWW;
  unsigned int* dst = imgbp + ((size_t)bm * DD + ds * 32) * (HWP / 2);
#pragma unroll
  for (int u = 0; u < 14; ++u) {
    int idx = tid + u * 256;  // 0..3583 = 32 rows x 112 pairs
    int dl = idx / 112, hp = idx - dl * 112;
    int hw = hp * 2;
    unsigned int lo = 0, hi = 0;
    if (hp < 98) {
      lo = f2bf(src[(size_t)dl * HWW + hw]);
      hi = f2bf(src[(size_t)dl * HWW + hw + 1]);
    }
    dst[(size_t)dl * (HWP / 2) + hp] = lo | (hi << 16);
  }
}

// P_imgT: image[bm][d][196] f32 -> imgbp2[bm][224][512] bf16 (transpose+pad)
__global__ void p_imgT(const float* __restrict__ image,
                       unsigned short* __restrict__ imgbp2) {
  __shared__ float tile[32][33];
  int bm = blockIdx.x;
  int hw0 = blockIdx.y * 32;  // 7 tiles cover 224
  int d0 = blockIdx.z * 32;
  int tx = threadIdx.x, ty = threadIdx.y;
  const float* src = image + ((size_t)bm * DD + d0) * HWW + hw0;
#pragma unroll
  for (int r = 0; r < 32; r += 8) {
    int d = r + ty;
    tile[d][tx] = (hw0 + tx < HWW) ? src[(size_t)d * HWW + tx] : 0.f;
  }
  __syncthreads();
  unsigned short* dst = imgbp2 + ((size_t)bm * HWP + hw0) * DD + d0;
#pragma unroll
  for (int r = 0; r < 32; r += 8) {
    int hwo = r + ty;
    dst[(size_t)hwo * DD + tx] = f2bf(tile[tx][hwo]);
  }
}

// K1: per (m, pair): S = e_j (64x512) . v^T via MFMA; wave-local column softmax;
// store a4 = exp(4*norm_sim) bf16 into attnR[pair][t][m*224+hw] (pad zeros);
// sbuf[pair][t][m] = sum_hw exp(ns); Abuf[pair][t] += sum a4.
__global__ void __launch_bounds__(256) k1_mfma(
    const unsigned short* __restrict__ eb,
    const unsigned short* __restrict__ imgbp2,
    unsigned short* __restrict__ attnR, float* __restrict__ sbuf,
    float* __restrict__ Abuf) {
  int m = blockIdx.x, pair = blockIdx.y;
  int i = pair >> 3, j = pair & 7;
  int tid = threadIdx.x;
  int w = tid >> 6, l = tid & 63;
  int g = l >> 4, c = l & 15;
  int bm = i * MM + m;

  __shared__ unsigned short vsb[HWP][40];  // [hw][k-pad] 17.9KB
  __shared__ float wsum_lds[TT][4];
  __shared__ float asum_lds[TT][4];

  const int nq = (w < 2) ? 4 : 3;  // hw-tiles: ht = w + 4*q
  f4v acc[4][4];                   // [q][tt]
#pragma unroll
  for (int q = 0; q < 4; ++q)
#pragma unroll
    for (int tt = 0; tt < 4; ++tt) acc[q][tt] = (f4v){0.f, 0.f, 0.f, 0.f};

  const unsigned short* ebase = eb + (size_t)j * TT * DD;
  const unsigned short* ibase = imgbp2 + (size_t)bm * HWP * DD;

  for (int kd = 0; kd < 16; ++kd) {
    int d0 = kd * 32;
    __syncthreads();
#pragma unroll
    for (int u = 0; u < 4; ++u) {
      int idx = tid + u * 256;
      if (idx < 896) {  // 224 rows x 4 b128
        int hwr = idx >> 2, qq = idx & 3;
        s8v v = *(const s8v*)(ibase + (size_t)hwr * DD + d0 + qq * 8);
        *(s8v*)&vsb[hwr][qq * 8] = v;
      }
    }
    __syncthreads();
    s8v Af[4];
#pragma unroll
    for (int tt = 0; tt < 4; ++tt)
      Af[tt] = *(const s8v*)(ebase + (size_t)(tt * 16 + c) * DD + d0 + g * 8);
    for (int q = 0; q < nq; ++q) {
      int ht = w + 4 * q;
      s8v Bf = *(const s8v*)&vsb[ht * 16 + c][g * 8];
#pragma unroll
      for (int tt = 0; tt < 4; ++tt)
        acc[q][tt] = __builtin_amdgcn_mfma_f32_16x16x32_bf16(Af[tt], Bf,
                                                             acc[q][tt], 0, 0, 0);
    }
  }

  // wave-local softmax over t (all 64 t live in this wave: tt x reg x g)
  float wpart[4][4], apart[4][4];
#pragma unroll
  for (int tt = 0; tt < 4; ++tt)
#pragma unroll
    for (int r = 0; r < 4; ++r) { wpart[tt][r] = 0.f; apart[tt][r] = 0.f; }

  unsigned short* arow = attnR + (size_t)pair * TT * NNP + m * HWP;
  for (int q = 0; q < nq; ++q) {
    int ht = w + 4 * q;
    int hw = ht * 16 + c;
    bool valid = hw < HWW;
    float mx = -3e38f;
#pragma unroll
    for (int tt = 0; tt < 4; ++tt)
#pragma unroll
      for (int r = 0; r < 4; ++r) mx = fmaxf(mx, acc[q][tt][r]);
    mx = fmaxf(mx, __shfl_xor(mx, 16, 64));
    mx = fmaxf(mx, __shfl_xor(mx, 32, 64));
    float z = 0.f;
#pragma unroll
    for (int tt = 0; tt < 4; ++tt)
#pragma unroll
      for (int r = 0; r < 4; ++r) {
        float p = expf(acc[q][tt][r] - mx);
        acc[q][tt][r] = p;
        z += p;
      }
    z += __shfl_xor(z, 16, 64);
    z += __shfl_xor(z, 32, 64);
    float rz = 1.f / z;
#pragma unroll
    for (int tt = 0; tt < 4; ++tt)
#pragma unroll
      for (int r = 0; r < 4; ++r) {
        float ns = acc[q][tt][r] * rz;
        float w1 = expf(ns);
        float a2 = w1 * w1;
        float a4 = a2 * a2;
        if (!valid) { w1 = 0.f; a4 = 0.f; }
        int t = tt * 16 + g * 4 + r;
        arow[(size_t)t * NNP + hw] = f2bf(a4);
        wpart[tt][r] += w1;
        apart[tt][r] += a4;
      }
  }
  // reduce over c-lanes (bits 0..3), then combine 4 waves via LDS
#pragma unroll
  for (int tt = 0; tt < 4; ++tt)
#pragma unroll
    for (int r = 0; r < 4; ++r) {
      float v1 = wpart[tt][r], v2 = apart[tt][r];
#pragma unroll
      for (int off = 1; off < 16; off <<= 1) {
        v1 += __shfl_xor(v1, off, 64);
        v2 += __shfl_xor(v2, off, 64);
      }
      wpart[tt][r] = v1;
      apart[tt][r] = v2;
    }
  if (c == 0) {
#pragma unroll
    for (int tt = 0; tt < 4; ++tt)
#pragma unroll
      for (int r = 0; r < 4; ++r) {
        int t = tt * 16 + g * 4 + r;
        wsum_lds[t][w] = wpart[tt][r];
        asum_lds[t][w] = apart[tt][r];
      }
  }
  __syncthreads();
  if (tid < TT) {
    float sw = wsum_lds[tid][0] + wsum_lds[tid][1] + wsum_lds[tid][2] +
               wsum_lds[tid][3];
    float sa = asum_lds[tid][0] + asum_lds[tid][1] + asum_lds[tid][2] +
               asum_lds[tid][3];
    sbuf[((size_t)pair * TT + tid) * MM + m] = sw;
    atomicAdd(&Abuf[pair * TT + tid], sa);
  }
}

// K2: vt_part[kslab][pair][t][d] = sum_{n in slab} a4[t][n] * v[n][d] via MFMA
__global__ void __launch_bounds__(256) k2_mfma(
    const unsigned short* __restrict__ attnR,
    const unsigned short* __restrict__ imgbp, float* __restrict__ vt_part) {
  int dh = blockIdx.x;     // 0..1 (d-half of 256)
  int kslab = blockIdx.y;  // 0..3 (2016 n each)
  int pair = blockIdx.z;
  int i = pair >> 3;
  int tid = threadIdx.x;
  int w = tid >> 6, l = tid & 63;
  int g = l >> 4, c = l & 15;
  int d0b = dh * 256;
  int kbase = kslab * 2016;

  __shared__ unsigned short asb[TT][40];   // 5.1KB
  __shared__ unsigned short bsb[256][40];  // 20.5KB

  f4v acc[4][4];  // [tt][dd]
#pragma unroll
  for (int tt = 0; tt < 4; ++tt)
#pragma unroll
    for (int dd = 0; dd < 4; ++dd) acc[tt][dd] = (f4v){0.f, 0.f, 0.f, 0.f};

  const unsigned short* abase = attnR + (size_t)pair * TT * NNP;

  for (int ks = 0; ks < 63; ++ks) {
    int n0 = kbase + ks * 32;
    int mi = n0 / HWP, hw0 = n0 - mi * HWP;
    const unsigned short* bbase =
        imgbp + ((size_t)(i * MM + mi) * DD + d0b) * HWP + hw0;
    __syncthreads();
    {  // stage A: 64 t-rows x 32 n
      int t = tid >> 2, qq = tid & 3;
      s8v va = *(const s8v*)(abase + (size_t)t * NNP + n0 + qq * 8);
      *(s8v*)&asb[t][qq * 8] = va;
    }
#pragma unroll
    for (int u = 0; u < 4; ++u) {  // stage B: 256 d-rows x 32 n
      int idx = tid + u * 256;
      int d = idx >> 2, qq = idx & 3;
      s8v vb = *(const s8v*)(bbase + (size_t)d * HWP + qq * 8);
      *(s8v*)&bsb[d][qq * 8] = vb;
    }
    __syncthreads();
    s8v Af[4];
#pragma unroll
    for (int tt = 0; tt < 4; ++tt)
      Af[tt] = *(const s8v*)&asb[tt * 16 + c][g * 8];
#pragma unroll
    for (int dd = 0; dd < 4; ++dd) {
      s8v Bf = *(const s8v*)&bsb[(w * 4 + dd) * 16 + c][g * 8];
#pragma unroll
      for (int tt = 0; tt < 4; ++tt)
        acc[tt][dd] = __builtin_amdgcn_mfma_f32_16x16x32_bf16(Af[tt], Bf,
                                                              acc[tt][dd], 0, 0, 0);
    }
  }
  float* op = vt_part + ((size_t)kslab * NPAIR + pair) * TT * DD;
#pragma unroll
  for (int tt = 0; tt < 4; ++tt)
#pragma unroll
    for (int dd = 0; dd < 4; ++dd)
#pragma unroll
      for (int r = 0; r < 4; ++r) {
        int t = tt * 16 + g * 4 + r;
        int d = d0b + (w * 4 + dd) * 16 + c;
        op[(size_t)t * DD + d] = acc[tt][dd][r];
      }
}

// K2b: v_tidal = (sum_s vt_part[s]) / A
__global__ void __launch_bounds__(256) k2b_reduce(
    const float* __restrict__ vt_part, const float* __restrict__ Abuf,
    float* __restrict__ v_tidal) {
  size_t f = (size_t)blockIdx.x * 256 + threadIdx.x;
  size_t base = f * 4;
  const size_t slab = (size_t)NPAIR * TT * DD;
  float rA = 1.f / Abuf[base >> 9];
  float4 s0 = *(const float4*)&vt_part[base];
  float4 s1 = *(const float4*)&vt_part[slab + base];
  float4 s2 = *(const float4*)&vt_part[2 * slab + base];
  float4 s3 = *(const float4*)&vt_part[3 * slab + base];
  float4 r;
  r.x = (s0.x + s1.x + s2.x + s3.x) * rA;
  r.y = (s0.y + s1.y + s2.y + s3.y) * rA;
  r.z = (s0.z + s1.z + s2.z + s3.z) * rA;
  r.w = (s0.w + s1.w + s2.w + s3.w) * rA;
  *(float4*)&v_tidal[base] = r;
}

// K3: diag[t] = dot(v_tidal[t], e[t]); r_qd = (1/G2) log sum exp(G2*diag)
__global__ void __launch_bounds__(256) k3_rqd(
    const float* __restrict__ v_tidal, const float* __restrict__ text,
    float* __restrict__ r_qd) {
  int pair = blockIdx.x;
  int j = pair & 7;
  int lane = threadIdx.x & 63, wid = threadIdx.x >> 6;
  __shared__ float dg[TT];
  for (int tt = 0; tt < 16; ++tt) {
    int t = wid * 16 + tt;
    const float* vt = v_tidal + ((size_t)pair * TT + t) * DD;
    const float* e = text + ((size_t)j * TT + t) * DD;
    float a = 0.f;
#pragma unroll
    for (int k = 0; k < 8; ++k) {
      int d = k * 64 + lane;
      a = fmaf(vt[d], e[d], a);
    }
    a = bflySum(a);
    if (lane == 0) dg[t] = a;
  }
  __syncthreads();
  if (threadIdx.x < TT) {
    float v = dg[threadIdx.x] * G2c;
    float mxv = bflyMax(v);
    float zz = bflySum(expf(v - mxv));
    if (threadIdx.x == 0) r_qd[pair] = (mxv + logf(zz)) / G2c;
  }
}

// K4: beta[t][m] = s[t][m] / sum_t s[t][m]
__global__ void __launch_bounds__(256) k4_beta(const float* __restrict__ sbuf,
                                               float* __restrict__ beta) {
  int pair = blockIdx.x;
  __shared__ float sl[TT * MM];
  __shared__ float ls[MM];
  for (int idx = threadIdx.x; idx < TT * MM; idx += 256)
    sl[idx] = sbuf[(size_t)pair * TT * MM + idx];
  __syncthreads();
  if (threadIdx.x < MM) {
    float a = 0.f;
    for (int t = 0; t < TT; ++t) a += sl[t * MM + threadIdx.x];
    ls[threadIdx.x] = 1.f / a;
  }
  __syncthreads();
  for (int idx = threadIdx.x; idx < TT * MM; idx += 256) {
    int mcol = idx % MM;
    beta[(size_t)pair * TT * MM + idx] = sl[idx] * ls[mcol];
  }
}

// K5: e_prime[m][d] = sum_t e[t][d]*beta[t][m]; ep_norm
__global__ void __launch_bounds__(256) k5_eprime(
    const float* __restrict__ text, const float* __restrict__ beta,
    float* __restrict__ e_prime, float* __restrict__ ep_norm) {
  int m = blockIdx.x, pair = blockIdx.y;
  int j = pair & 7;
  int d = threadIdx.x * 2;
  float a0 = 0.f, a1 = 0.f;
  const float* bt = beta + (size_t)pair * TT * MM + m;
  const float* e = text + (size_t)j * TT * DD + d;
  for (int t = 0; t < TT; ++t) {
    float b = bt[t * MM];
    float2 ev = *(const float2*)(e + (size_t)t * DD);
    a0 = fmaf(ev.x, b, a0);
    a1 = fmaf(ev.y, b, a1);
  }
  *(float2*)(e_prime + ((size_t)pair * MM + m) * DD + d) = make_float2(a0, a1);
  __shared__ float buf[4];
  float nr = bflySum(a0 * a0 + a1 * a1);
  int lane = threadIdx.x & 63, wid = threadIdx.x >> 6;
  if (lane == 0) buf[wid] = nr;
  __syncthreads();
  if (threadIdx.x == 0)
    ep_norm[pair * MM + m] = sqrtf(buf[0] + buf[1] + buf[2] + buf[3]);
}

// K6: ref[m] via cosine similarity
__global__ void __launch_bounds__(256) k6_ref(
    const float* __restrict__ image, const float* __restrict__ e_prime,
    const float* __restrict__ ep_norm, float* __restrict__ refb) {
  int m = blockIdx.x, pair = blockIdx.y;
  int i = pair >> 3;
  int tid = threadIdx.x;
  bool act = tid < HWW;
  int hw = act ? tid : (HWW - 1);
  const float* vimg = image + ((size_t)(i * MM + m) * DD) * HWW + hw;
  const float* ep = e_prime + ((size_t)pair * MM + m) * DD;
  float ve = 0.f, rn2 = 0.f;
  for (int d = 0; d < DD; d += 4) {
#pragma unroll
    for (int k = 0; k < 4; ++k) {
      float vv = vimg[(size_t)(d + k) * HWW];
      ve = fmaf(vv, ep[d + k], ve);
      rn2 = fmaf(vv, vv, rn2);
    }
  }
  float en = ep_norm[pair * MM + m];
  float val = act ? (ve / (sqrtf(rn2) * en)) : 0.f;
  val = bflySum(val);
  __shared__ float buf[4];
  int lane = tid & 63, wid = tid >> 6;
  if (lane == 0) buf[wid] = val;
  __syncthreads();
  if (tid == 0)
    refb[pair * MM + m] = (buf[0] + buf[1] + buf[2] + buf[3]) * (1.0f / HWW);
}

// K7: S = r_qd + (1/G2) log sum_m exp(ref[m])
__global__ void k7_S(const float* __restrict__ refb,
                     const float* __restrict__ r_qd, float* __restrict__ Sb) {
  int pair = threadIdx.x;
  if (pair >= NPAIR) return;
  const float* r = refb + pair * MM;
  float mx = -1e30f;
  for (int mi = 0; mi < MM; ++mi) mx = fmaxf(mx, r[mi]);
  float z = 0.f;
  for (int mi = 0; mi < MM; ++mi) z += expf(r[mi] - mx);
  Sb[pair] = r_qd[pair] + (mx + logf(z)) / G2c;
}

// K8: final scalar loss
__global__ void __launch_bounds__(256) k8_loss(
    const float* __restrict__ Sb, const float* __restrict__ beta,
    const int* __restrict__ spinds, float* __restrict__ out) {
  __shared__ float bb[TT * MM];
  __shared__ float buf[4];
  __shared__ float sreg;
  int tid = threadIdx.x;
  if (tid == 0) sreg = 0.f;
  __syncthreads();
  for (int b = 0; b < BB; ++b) {
    size_t base = (size_t)(b * BB + b) * TT * MM;
    for (int idx = tid; idx < TT * MM; idx += 256) bb[idx] = beta[base + idx];
    __syncthreads();
    float val = 0.f;
    for (int k = 0; k < 16; ++k) {
      int idx = tid + k * 256;
      int t = idx >> 6, s2 = idx & 63;
      if (t != s2) {
        float dot = 0.f;
        for (int mi = 0; mi < MM; ++mi)
          dot = fmaf(bb[t * MM + mi], bb[s2 * MM + mi], dot);
        val += dot * dot;
      }
    }
    val = bflySum(val);
    int lane = tid & 63, wid = tid >> 6;
    if (lane == 0) buf[wid] = val;
    __syncthreads();
    if (tid == 0) sreg += sqrtf(fmaxf(buf[0] + buf[1] + buf[2] + buf[3], 0.f));
    __syncthreads();
  }
  if (tid == 0) {
    float l1 = 0.f, l2 = 0.f;
    for (int i = 0; i < BB; ++i) {
      float num = G3c * expf(Sb[i * BB + i]);
      float pdq = 0.f, pqd = 0.f;
      for (int k = 0; k < 5; ++k) {
        int kk = spinds[i * 5 + k];
        pdq += G3c * expf(Sb[i * BB + kk]);
        pqd += G3c * expf(Sb[kk * BB + i]);
      }
      l1 += num / pdq;
      l2 += num / pqd;
    }
    out[0] = -(l1 / BB) - (l2 / BB) + sreg / (float)(BB * TT * MM);
  }
}

extern "C" void kernel_launch(void* const* d_in, const int* in_sizes, int n_in,
                              void* d_out, int out_size, void* d_ws,
                              size_t ws_size, hipStream_t stream) {
  const float* image = (const float*)d_in[0];
  const float* text = (const float*)d_in[1];
  const int* spinds = (const int*)d_in[3];
  float* out = (float*)d_out;

  float* ws = (float*)d_ws;
  size_t off = 0;
  unsigned short* attnR = (unsigned short*)(ws + off);
  off += (size_t)NPAIR * TT * NNP / 2;  // 16.5M floats (bf16 x 33M)
  unsigned short* imgbp = (unsigned short*)(ws + off);
  off += (size_t)BB * MM * DD * HWP / 2;  // 16.5M floats
  unsigned short* imgbp2 = (unsigned short*)(ws + off);
  off += (size_t)BB * MM * HWP * DD / 2;  // 16.5M floats
  float* vt_part = (float*)imgbp2;        // alias: imgbp2 dead after k1
  unsigned short* eb = (unsigned short*)(ws + off);
  off += (size_t)BB * TT * DD / 2;  // 131072 floats
  float* Abuf = ws + off;    off += (size_t)NPAIR * TT;
  float* v_tidal = ws + off; off += (size_t)NPAIR * TT * DD;
  float* sbuf = ws + off;    off += (size_t)NPAIR * TT * MM;
  float* beta = ws + off;    off += (size_t)NPAIR * TT * MM;
  float* e_prime = ws + off; off += (size_t)NPAIR * MM * DD;
  float* ep_norm = ws + off; off += (size_t)NPAIR * MM;
  float* refb = ws + off;    off += (size_t)NPAIR * MM;
  float* r_qd = ws + off;    off += (size_t)NPAIR;
  float* Sb = ws + off;      off += (size_t)NPAIR;

  hipMemsetAsync(Abuf, 0, (size_t)NPAIR * TT * sizeof(float), stream);

  p_text<<<1024, 256, 0, stream>>>(text, eb);
  p_img<<<dim3(BB * MM, 16), 256, 0, stream>>>(image, (unsigned int*)imgbp);
  p_imgT<<<dim3(BB * MM, 7, 16), dim3(32, 8), 0, stream>>>(image, imgbp2);
  k1_mfma<<<dim3(MM, NPAIR), 256, 0, stream>>>(eb, imgbp2, attnR, sbuf, Abuf);
  k2_mfma<<<dim3(2, 4, NPAIR), 256, 0, stream>>>(attnR, imgbp, vt_part);
  k2b_reduce<<<2048, 256, 0, stream>>>(vt_part, Abuf, v_tidal);
  k3_rqd<<<NPAIR, 256, 0, stream>>>(v_tidal, text, r_qd);
  k4_beta<<<NPAIR, 256, 0, stream>>>(sbuf, beta);
  k5_eprime<<<dim3(MM, NPAIR), 256, 0, stream>>>(text, beta, e_prime, ep_norm);
  k6_ref<<<dim3(MM, NPAIR), 256, 0, stream>>>(image, e_prime, ep_norm, refb);
  k7_S<<<1, 64, 0, stream>>>(refb, r_qd, Sb);
  k8_loss<<<1, 256, 0, stream>>>(Sb, beta, spinds, out);
}

// Round 8
// 718.251 us; speedup vs baseline: 6.1502x; 1.7736x over previous
//
#include <hip/hip_runtime.h>
#include <hip/hip_bf16.h>
#include <cstdint>

#define BB 8
#define MM 36
#define DD 512
#define TT 64
#define HWW 196
#define HWP 224   /* hw padded to 14*16 */
#define NN 7056
#define NNP 8064  /* MM*HWP */
#define NCK 252   /* NNP/32 n-chunks per batch */
#define NPAIR 64
#define G2c 5.0f
#define G3c 10.0f

typedef __attribute__((ext_vector_type(8))) short s8v;
typedef __attribute__((ext_vector_type(4))) float f4v;

__device__ __forceinline__ float bflySum(float v) {
#pragma unroll
  for (int off = 32; off > 0; off >>= 1) v += __shfl_xor(v, off, 64);
  return v;
}
__device__ __forceinline__ float bflyMax(float v) {
#pragma unroll
  for (int off = 32; off > 0; off >>= 1) v = fmaxf(v, __shfl_xor(v, off, 64));
  return v;
}
__device__ __forceinline__ unsigned short f2bf(float x) {
  __hip_bfloat16 h = __float2bfloat16(x);
  return *(unsigned short*)&h;
}
__device__ __forceinline__ float bf2f(unsigned short u) {
  unsigned int x = ((unsigned int)u) << 16;
  return __uint_as_float(x);
}

// P_text: text f32 -> eb bf16 (flat 262144)
__global__ void p_text(const float* __restrict__ text,
                       unsigned short* __restrict__ eb) {
  int idx = blockIdx.x * 256 + threadIdx.x;
  eb[idx] = f2bf(text[idx]);
}

// P_img: image[bm][d][196] f32 -> imgbp[bm][d][224] bf16 (pad zeros)
__global__ void __launch_bounds__(256) p_img(const float* __restrict__ image,
                                             unsigned int* __restrict__ imgbp) {
  int bm = blockIdx.x, ds = blockIdx.y;
  int tid = threadIdx.x;
  const float* src = image + ((size_t)bm * DD + ds * 32) * HWW;
  unsigned int* dst = imgbp + ((size_t)bm * DD + ds * 32) * (HWP / 2);
#pragma unroll
  for (int u = 0; u < 14; ++u) {
    int idx = tid + u * 256;  // 0..3583 = 32 rows x 112 pairs
    int dl = idx / 112, hp = idx - dl * 112;
    int hw = hp * 2;
    unsigned int lo = 0, hi = 0;
    if (hp < 98) {
      lo = f2bf(src[(size_t)dl * HWW + hw]);
      hi = f2bf(src[(size_t)dl * HWW + hw + 1]);
    }
    dst[(size_t)dl * (HWP / 2) + hp] = lo | (hi << 16);
  }
}

// P_imgT: image[bm][d][196] f32 -> imgbp2[bm][224][512] bf16 (transpose+pad)
__global__ void p_imgT(const float* __restrict__ image,
                       unsigned short* __restrict__ imgbp2) {
  __shared__ float tile[32][33];
  int bm = blockIdx.x;
  int hw0 = blockIdx.y * 32;  // 7 tiles cover 224
  int d0 = blockIdx.z * 32;
  int tx = threadIdx.x, ty = threadIdx.y;
  const float* src = image + ((size_t)bm * DD + d0) * HWW + hw0;
#pragma unroll
  for (int r = 0; r < 32; r += 8) {
    int d = r + ty;
    tile[d][tx] = (hw0 + tx < HWW) ? src[(size_t)d * HWW + tx] : 0.f;
  }
  __syncthreads();
  unsigned short* dst = imgbp2 + ((size_t)bm * HWP + hw0) * DD + d0;
#pragma unroll
  for (int r = 0; r < 32; r += 8) {
    int hwo = r + ty;
    dst[(size_t)hwo * DD + tx] = f2bf(tile[tx][hwo]);
  }
}

// K1: per (ck, i): compute sim for all 8 j x 64 t vs 32 v-rows via MFMA.
// E_all (512x512 bf16, 512KB) stays L2-hot; imgbp2 read exactly once.
// Writes attnR chunk-major [pair][ck][t][32] via LDS transpose (coalesced),
// plus per-chunk column-sum partials wpartg/apartg (no atomics).
__global__ void __launch_bounds__(256) k1_mfma(
    const unsigned short* __restrict__ eb,      // [8*64][512]
    const unsigned short* __restrict__ imgbp2,  // [bm][224][512]
    unsigned short* __restrict__ attnR,         // [pair][252][64][32]
    float* __restrict__ wpartg, float* __restrict__ apartg) {
  int ck = blockIdx.x;  // 0..251
  int i = blockIdx.y;   // 0..7
  int mi = ck / 7;
  int hwb = (ck - mi * 7) * 32;  // 0..192 step 32
  int bm = i * MM + mi;
  int tid = threadIdx.x;
  int w = tid >> 6, l = tid & 63;
  int g = l >> 4, c = l & 15;

  __shared__ unsigned short vsb[32][520];  // 33.3KB, stride 520 -> bank-spread
  __shared__ unsigned short trb[512 * 32];  // 32KB == attnR chunk flat layout

  // one-shot stage: 32 v-rows x 512 d (coalesced b128)
  const unsigned short* vsrc = imgbp2 + ((size_t)bm * HWP + hwb) * DD;
#pragma unroll
  for (int k = 0; k < 8; ++k) {
    int flat = tid * 8 + k * 2048;
    int row = flat >> 9, col = flat & 511;
    *(s8v*)&vsb[row][col] = *(const s8v*)(vsrc + (size_t)row * DD + col);
  }
  __syncthreads();

  f4v acc[8][2];  // [q (tAll-tile w*8+q)][nt]
#pragma unroll
  for (int q = 0; q < 8; ++q)
#pragma unroll
    for (int nt = 0; nt < 2; ++nt) acc[q][nt] = (f4v){0.f, 0.f, 0.f, 0.f};

  for (int ks = 0; ks < 16; ++ks) {
    int d0 = ks * 32;
    s8v Bf0 = *(const s8v*)&vsb[c][d0 + g * 8];
    s8v Bf1 = *(const s8v*)&vsb[16 + c][d0 + g * 8];
#pragma unroll
    for (int q = 0; q < 8; ++q) {
      s8v Af = *(const s8v*)(eb + ((size_t)((w * 8 + q) * 16 + c)) * DD + d0 +
                             g * 8);
      acc[q][0] = __builtin_amdgcn_mfma_f32_16x16x32_bf16(Af, Bf0, acc[q][0], 0, 0, 0);
      acc[q][1] = __builtin_amdgcn_mfma_f32_16x16x32_bf16(Af, Bf1, acc[q][1], 0, 0, 0);
    }
  }

  // softmax over t per (jj, nt): reduce over q-subset+r regs, then g-lanes
  float rz[2][2];
#pragma unroll
  for (int jj = 0; jj < 2; ++jj)
#pragma unroll
    for (int nt = 0; nt < 2; ++nt) {
      float mx = -3e38f;
#pragma unroll
      for (int qq = 0; qq < 4; ++qq)
#pragma unroll
        for (int r = 0; r < 4; ++r) mx = fmaxf(mx, acc[jj * 4 + qq][nt][r]);
      mx = fmaxf(mx, __shfl_xor(mx, 16, 64));
      mx = fmaxf(mx, __shfl_xor(mx, 32, 64));
      float z = 0.f;
#pragma unroll
      for (int qq = 0; qq < 4; ++qq)
#pragma unroll
        for (int r = 0; r < 4; ++r) {
          float p = expf(acc[jj * 4 + qq][nt][r] - mx);
          acc[jj * 4 + qq][nt][r] = p;
          z += p;
        }
      z += __shfl_xor(z, 16, 64);
      z += __shfl_xor(z, 32, 64);
      rz[jj][nt] = 1.f / z;
    }

  // a4 = exp(4*ns) = exp(ns)^4; dump to trb; accumulate column sums
#pragma unroll
  for (int q = 0; q < 8; ++q) {
    int jj = q >> 2;
#pragma unroll
    for (int r = 0; r < 4; ++r) {
      float wp = 0.f, ap = 0.f;
#pragma unroll
      for (int nt = 0; nt < 2; ++nt) {
        float ns = acc[q][nt][r] * rz[jj][nt];
        float w1 = expf(ns);
        float a2 = w1 * w1;
        float a4 = a2 * a2;
        bool valid = (hwb + nt * 16 + c) < HWW;
        float a4m = valid ? a4 : 0.f;
        trb[((w * 8 + q) * 16 + g * 4 + r) * 32 + nt * 16 + c] = f2bf(a4m);
        wp += valid ? w1 : 0.f;
        ap += a4m;
      }
#pragma unroll
      for (int off = 1; off < 16; off <<= 1) {
        wp += __shfl_xor(wp, off, 64);
        ap += __shfl_xor(ap, off, 64);
      }
      if (c == 0) {
        int t = (q & 3) * 16 + g * 4 + r;
        size_t pidx = ((size_t)(i * 8 + 2 * w + jj) * NCK + ck) * 64 + t;
        wpartg[pidx] = wp;
        apartg[pidx] = ap;
      }
    }
  }
  __syncthreads();
  // linear coalesced copy trb -> attnR (8 pairs x 4KB)
#pragma unroll
  for (int j = 0; j < 8; ++j) {
    unsigned short* dst =
        attnR + ((size_t)(i * 8 + j) * NCK + ck) * 2048 + tid * 8;
    *(s8v*)dst = *(const s8v*)&trb[j * 2048 + tid * 8];
  }
}

// K_red: Abuf[pair][t] = sum_ck apart; sbuf[pair][t][m] = sum_{cc<7} wpart
__global__ void __launch_bounds__(256) k_red(const float* __restrict__ wpartg,
                                             const float* __restrict__ apartg,
                                             float* __restrict__ sbuf,
                                             float* __restrict__ Abuf) {
  int pair = blockIdx.x;
  int tid = threadIdx.x;
  int t = tid & 63, part = tid >> 6;
  float s = 0.f;
  for (int ck = part; ck < NCK; ck += 4)
    s += apartg[((size_t)pair * NCK + ck) * 64 + t];
  __shared__ float ab[4][64];
  ab[part][t] = s;
  __syncthreads();
  if (tid < 64)
    Abuf[pair * 64 + tid] = ab[0][tid] + ab[1][tid] + ab[2][tid] + ab[3][tid];
  for (int idx = tid; idx < 64 * MM; idx += 256) {
    int tt = idx / MM, m = idx - (idx / MM) * MM;
    float ss = 0.f;
#pragma unroll
    for (int cc = 0; cc < 7; ++cc)
      ss += wpartg[((size_t)pair * NCK + m * 7 + cc) * 64 + tt];
    sbuf[((size_t)pair * TT + tt) * MM + m] = ss;
  }
}

// K2: vt_part[kslab][pair][t][d] = sum_{n in slab} a4[t][n] * v[n][d] via MFMA
__global__ void __launch_bounds__(256) k2_mfma(
    const unsigned short* __restrict__ attnR,
    const unsigned short* __restrict__ imgbp, float* __restrict__ vt_part) {
  int dh = blockIdx.x;     // 0..1 (d-half of 256)
  int kslab = blockIdx.y;  // 0..1 (4032 n each)
  int pair = blockIdx.z;
  int i = pair >> 3;
  int tid = threadIdx.x;
  int w = tid >> 6, l = tid & 63;
  int g = l >> 4, c = l & 15;
  int d0b = dh * 256;

  __shared__ unsigned short asb[TT][40];   // 5.1KB
  __shared__ unsigned short bsb[256][40];  // 20.5KB

  f4v acc[4][4];  // [tt][dd]
#pragma unroll
  for (int tt = 0; tt < 4; ++tt)
#pragma unroll
    for (int dd = 0; dd < 4; ++dd) acc[tt][dd] = (f4v){0.f, 0.f, 0.f, 0.f};

  for (int ks = 0; ks < 126; ++ks) {
    int ckg = kslab * 126 + ks;
    int n0 = ckg * 32;
    int mi = n0 / HWP, hw0 = n0 - mi * HWP;
    const unsigned short* bbase =
        imgbp + ((size_t)(i * MM + mi) * DD + d0b) * HWP + hw0;
    __syncthreads();
    {  // stage A: chunk-major attnR -> fully coalesced 4KB
      const unsigned short* ach = attnR + ((size_t)pair * NCK + ckg) * 2048;
      int t = tid >> 2, qq = tid & 3;
      *(s8v*)&asb[t][qq * 8] = *(const s8v*)(ach + tid * 8);
    }
#pragma unroll
    for (int u = 0; u < 4; ++u) {  // stage B: 256 d-rows x 32 n
      int idx = tid + u * 256;
      int d = idx >> 2, qq = idx & 3;
      *(s8v*)&bsb[d][qq * 8] = *(const s8v*)(bbase + (size_t)d * HWP + qq * 8);
    }
    __syncthreads();
    s8v Af[4];
#pragma unroll
    for (int tt = 0; tt < 4; ++tt)
      Af[tt] = *(const s8v*)&asb[tt * 16 + c][g * 8];
#pragma unroll
    for (int dd = 0; dd < 4; ++dd) {
      s8v Bf = *(const s8v*)&bsb[(w * 4 + dd) * 16 + c][g * 8];
#pragma unroll
      for (int tt = 0; tt < 4; ++tt)
        acc[tt][dd] = __builtin_amdgcn_mfma_f32_16x16x32_bf16(Af[tt], Bf,
                                                              acc[tt][dd], 0, 0, 0);
    }
  }
  float* op = vt_part + ((size_t)kslab * NPAIR + pair) * TT * DD;
#pragma unroll
  for (int tt = 0; tt < 4; ++tt)
#pragma unroll
    for (int dd = 0; dd < 4; ++dd)
#pragma unroll
      for (int r = 0; r < 4; ++r) {
        int t = tt * 16 + g * 4 + r;
        int d = d0b + (w * 4 + dd) * 16 + c;
        op[(size_t)t * DD + d] = acc[tt][dd][r];
      }
}

// K2b: v_tidal = (sum of 2 slabs) / A
__global__ void __launch_bounds__(256) k2b_reduce(
    const float* __restrict__ vt_part, const float* __restrict__ Abuf,
    float* __restrict__ v_tidal) {
  size_t f = (size_t)blockIdx.x * 256 + threadIdx.x;
  size_t base = f * 4;
  const size_t slab = (size_t)NPAIR * TT * DD;
  float rA = 1.f / Abuf[base >> 9];
  float4 s0 = *(const float4*)&vt_part[base];
  float4 s1 = *(const float4*)&vt_part[slab + base];
  float4 r;
  r.x = (s0.x + s1.x) * rA;
  r.y = (s0.y + s1.y) * rA;
  r.z = (s0.z + s1.z) * rA;
  r.w = (s0.w + s1.w) * rA;
  *(float4*)&v_tidal[base] = r;
}

// K3: diag[t] = dot(v_tidal[t], e[t]); r_qd = (1/G2) log sum exp(G2*diag)
__global__ void __launch_bounds__(256) k3_rqd(
    const float* __restrict__ v_tidal, const float* __restrict__ text,
    float* __restrict__ r_qd) {
  int pair = blockIdx.x;
  int j = pair & 7;
  int lane = threadIdx.x & 63, wid = threadIdx.x >> 6;
  __shared__ float dg[TT];
  for (int tt = 0; tt < 16; ++tt) {
    int t = wid * 16 + tt;
    const float* vt = v_tidal + ((size_t)pair * TT + t) * DD;
    const float* e = text + ((size_t)j * TT + t) * DD;
    float a = 0.f;
#pragma unroll
    for (int k = 0; k < 8; ++k) {
      int d = k * 64 + lane;
      a = fmaf(vt[d], e[d], a);
    }
    a = bflySum(a);
    if (lane == 0) dg[t] = a;
  }
  __syncthreads();
  if (threadIdx.x < TT) {
    float v = dg[threadIdx.x] * G2c;
    float mxv = bflyMax(v);
    float zz = bflySum(expf(v - mxv));
    if (threadIdx.x == 0) r_qd[pair] = (mxv + logf(zz)) / G2c;
  }
}

// K4: beta[t][m] = s[t][m] / sum_t s[t][m]
__global__ void __launch_bounds__(256) k4_beta(const float* __restrict__ sbuf,
                                               float* __restrict__ beta) {
  int pair = blockIdx.x;
  __shared__ float sl[TT * MM];
  __shared__ float ls[MM];
  for (int idx = threadIdx.x; idx < TT * MM; idx += 256)
    sl[idx] = sbuf[(size_t)pair * TT * MM + idx];
  __syncthreads();
  if (threadIdx.x < MM) {
    float a = 0.f;
    for (int t = 0; t < TT; ++t) a += sl[t * MM + threadIdx.x];
    ls[threadIdx.x] = 1.f / a;
  }
  __syncthreads();
  for (int idx = threadIdx.x; idx < TT * MM; idx += 256) {
    int mcol = idx % MM;
    beta[(size_t)pair * TT * MM + idx] = sl[idx] * ls[mcol];
  }
}

// K5: e_prime[m][d] = sum_t e[t][d]*beta[t][m]; ep_norm
__global__ void __launch_bounds__(256) k5_eprime(
    const float* __restrict__ text, const float* __restrict__ beta,
    float* __restrict__ e_prime, float* __restrict__ ep_norm) {
  int m = blockIdx.x, pair = blockIdx.y;
  int j = pair & 7;
  int d = threadIdx.x * 2;
  float a0 = 0.f, a1 = 0.f;
  const float* bt = beta + (size_t)pair * TT * MM + m;
  const float* e = text + (size_t)j * TT * DD + d;
  for (int t = 0; t < TT; ++t) {
    float b = bt[t * MM];
    float2 ev = *(const float2*)(e + (size_t)t * DD);
    a0 = fmaf(ev.x, b, a0);
    a1 = fmaf(ev.y, b, a1);
  }
  *(float2*)(e_prime + ((size_t)pair * MM + m) * DD + d) = make_float2(a0, a1);
  __shared__ float buf[4];
  float nr = bflySum(a0 * a0 + a1 * a1);
  int lane = threadIdx.x & 63, wid = threadIdx.x >> 6;
  if (lane == 0) buf[wid] = nr;
  __syncthreads();
  if (threadIdx.x == 0)
    ep_norm[pair * MM + m] = sqrtf(buf[0] + buf[1] + buf[2] + buf[3]);
}

// K6: ref[m] via cosine sim, reading bf16 v-rows coalesced (wave per row)
__global__ void __launch_bounds__(256) k6_ref(
    const unsigned short* __restrict__ imgbp2,
    const float* __restrict__ e_prime, const float* __restrict__ ep_norm,
    float* __restrict__ refb) {
  int m = blockIdx.x, pair = blockIdx.y;
  int i = pair >> 3;
  int bm = i * MM + m;
  int tid = threadIdx.x, w = tid >> 6, l = tid & 63;
  const float* ep = e_prime + ((size_t)pair * MM + m) * DD + l * 8;
  float4 e0 = *(const float4*)ep;
  float4 e1 = *(const float4*)(ep + 4);
  float epr[8] = {e0.x, e0.y, e0.z, e0.w, e1.x, e1.y, e1.z, e1.w};
  float ren = 1.f / ep_norm[pair * MM + m];
  float accv = 0.f;
  for (int k = 0; k < 49; ++k) {
    int hw = w + 4 * k;  // 4 waves x 49 = 196
    s8v v8 = *(const s8v*)(imgbp2 + ((size_t)bm * HWP + hw) * DD + l * 8);
    float ve = 0.f, rn = 0.f;
#pragma unroll
    for (int e = 0; e < 8; ++e) {
      float vv = bf2f((unsigned short)v8[e]);
      ve = fmaf(vv, epr[e], ve);
      rn = fmaf(vv, vv, rn);
    }
    ve = bflySum(ve);
    rn = bflySum(rn);
    accv += ve * rsqrtf(rn) * ren;
  }
  __shared__ float buf[4];
  if (l == 0) buf[w] = accv;
  __syncthreads();
  if (tid == 0)
    refb[pair * MM + m] = (buf[0] + buf[1] + buf[2] + buf[3]) * (1.0f / HWW);
}

// K7: S = r_qd + (1/G2) log sum_m exp(ref[m])
__global__ void k7_S(const float* __restrict__ refb,
                     const float* __restrict__ r_qd, float* __restrict__ Sb) {
  int pair = threadIdx.x;
  if (pair >= NPAIR) return;
  const float* r = refb + pair * MM;
  float mx = -1e30f;
  for (int mi = 0; mi < MM; ++mi) mx = fmaxf(mx, r[mi]);
  float z = 0.f;
  for (int mi = 0; mi < MM; ++mi) z += expf(r[mi] - mx);
  Sb[pair] = r_qd[pair] + (mx + logf(z)) / G2c;
}

// K8a: per-b beta-regularizer partial
__global__ void __launch_bounds__(256) k8a(const float* __restrict__ beta,
                                           float* __restrict__ sregs) {
  int b = blockIdx.x;
  __shared__ float bb[TT * MM];
  __shared__ float buf[4];
  int tid = threadIdx.x;
  size_t base = (size_t)(b * BB + b) * TT * MM;
  for (int idx = tid; idx < TT * MM; idx += 256) bb[idx] = beta[base + idx];
  __syncthreads();
  float val = 0.f;
  for (int k = 0; k < 16; ++k) {
    int idx = tid + k * 256;
    int t = idx >> 6, s2 = idx & 63;
    if (t != s2) {
      float dot = 0.f;
      for (int mi = 0; mi < MM; ++mi)
        dot = fmaf(bb[t * MM + mi], bb[s2 * MM + mi], dot);
      val += dot * dot;
    }
  }
  val = bflySum(val);
  int lane = tid & 63, wid = tid >> 6;
  if (lane == 0) buf[wid] = val;
  __syncthreads();
  if (tid == 0) sregs[b] = sqrtf(fmaxf(buf[0] + buf[1] + buf[2] + buf[3], 0.f));
}

// K8b: final scalar loss
__global__ void k8b(const float* __restrict__ Sb,
                    const float* __restrict__ sregs,
                    const int* __restrict__ spinds, float* __restrict__ out) {
  if (threadIdx.x != 0) return;
  float sreg = 0.f;
  for (int b = 0; b < BB; ++b) sreg += sregs[b];
  float l1 = 0.f, l2 = 0.f;
  for (int i = 0; i < BB; ++i) {
    float num = G3c * expf(Sb[i * BB + i]);
    float pdq = 0.f, pqd = 0.f;
    for (int k = 0; k < 5; ++k) {
      int kk = spinds[i * 5 + k];
      pdq += G3c * expf(Sb[i * BB + kk]);
      pqd += G3c * expf(Sb[kk * BB + i]);
    }
    l1 += num / pdq;
    l2 += num / pqd;
  }
  out[0] = -(l1 / BB) - (l2 / BB) + sreg / (float)(BB * TT * MM);
}

extern "C" void kernel_launch(void* const* d_in, const int* in_sizes, int n_in,
                              void* d_out, int out_size, void* d_ws,
                              size_t ws_size, hipStream_t stream) {
  const float* image = (const float*)d_in[0];
  const float* text = (const float*)d_in[1];
  const int* spinds = (const int*)d_in[3];
  float* out = (float*)d_out;

  float* ws = (float*)d_ws;
  size_t off = 0;
  unsigned short* attnR = (unsigned short*)(ws + off);
  off += (size_t)NPAIR * NCK * 2048 / 2;  // 16.5M floats (66MB bf16)
  unsigned short* imgbp = (unsigned short*)(ws + off);
  off += (size_t)BB * MM * DD * HWP / 2;  // 16.5M
  unsigned short* imgbp2 = (unsigned short*)(ws + off);
  off += (size_t)BB * MM * HWP * DD / 2;  // 16.5M
  float* vt_part = ws + off; off += (size_t)2 * NPAIR * TT * DD;  // 4.2M
  unsigned short* eb = (unsigned short*)(ws + off);
  off += (size_t)BB * TT * DD / 2;
  float* wpartg = ws + off;  off += (size_t)NPAIR * NCK * 64;  // 1.03M
  float* apartg = ws + off;  off += (size_t)NPAIR * NCK * 64;  // 1.03M
  float* Abuf = ws + off;    off += (size_t)NPAIR * TT;
  float* v_tidal = ws + off; off += (size_t)NPAIR * TT * DD;
  float* sbuf = ws + off;    off += (size_t)NPAIR * TT * MM;
  float* beta = ws + off;    off += (size_t)NPAIR * TT * MM;
  float* e_prime = ws + off; off += (size_t)NPAIR * MM * DD;
  float* ep_norm = ws + off; off += (size_t)NPAIR * MM;
  float* refb = ws + off;    off += (size_t)NPAIR * MM;
  float* r_qd = ws + off;    off += (size_t)NPAIR;
  float* Sb = ws + off;      off += (size_t)NPAIR;
  float* sregs = ws + off;   off += (size_t)BB;

  p_text<<<1024, 256, 0, stream>>>(text, eb);
  p_img<<<dim3(BB * MM, 16), 256, 0, stream>>>(image, (unsigned int*)imgbp);
  p_imgT<<<dim3(BB * MM, 7, 16), dim3(32, 8), 0, stream>>>(image, imgbp2);
  k1_mfma<<<dim3(NCK, BB), 256, 0, stream>>>(eb, imgbp2, attnR, wpartg, apartg);
  k_red<<<NPAIR, 256, 0, stream>>>(wpartg, apartg, sbuf, Abuf);
  k2_mfma<<<dim3(2, 2, NPAIR), 256, 0, stream>>>(attnR, imgbp, vt_part);
  k2b_reduce<<<2048, 256, 0, stream>>>(vt_part, Abuf, v_tidal);
  k3_rqd<<<NPAIR, 256, 0, stream>>>(v_tidal, text, r_qd);
  k4_beta<<<NPAIR, 256, 0, stream>>>(sbuf, beta);
  k5_eprime<<<dim3(MM, NPAIR), 256, 0, stream>>>(text, beta, e_prime, ep_norm);
  k6_ref<<<dim3(MM, NPAIR), 256, 0, stream>>>(imgbp2, e_prime, ep_norm, refb);
  k7_S<<<1, 64, 0, stream>>>(refb, r_qd, Sb);
  k8a<<<BB, 256, 0, stream>>>(beta, sregs);
  k8b<<<1, 64, 0, stream>>>(Sb, sregs, spinds, out);
}

// Round 13
// 658.749 us; speedup vs baseline: 6.7057x; 1.0903x over previous
//
#include <hip/hip_runtime.h>
#include <hip/hip_bf16.h>
#include <cstdint>

#define BB 8
#define MM 36
#define DD 512
#define TT 64
#define HWW 196
#define HWP 224   /* hw padded to 14*16 */
#define NN 7056
#define NNP 8064  /* MM*HWP */
#define NCK 252   /* NNP/32 n-chunks per batch */
#define NPAIR 64
#define G2c 5.0f
#define G3c 10.0f

typedef __attribute__((ext_vector_type(8))) short s8v;
typedef __attribute__((ext_vector_type(4))) float f4v;

__device__ __forceinline__ float bflySum(float v) {
#pragma unroll
  for (int off = 32; off > 0; off >>= 1) v += __shfl_xor(v, off, 64);
  return v;
}
__device__ __forceinline__ float bflyMax(float v) {
#pragma unroll
  for (int off = 32; off > 0; off >>= 1) v = fmaxf(v, __shfl_xor(v, off, 64));
  return v;
}
__device__ __forceinline__ unsigned short f2bf(float x) {
  __hip_bfloat16 h = __float2bfloat16(x);
  return *(unsigned short*)&h;
}
__device__ __forceinline__ float bf2f(unsigned short u) {
  unsigned int x = ((unsigned int)u) << 16;
  return __uint_as_float(x);
}

// P_text: text f32 -> eb bf16 (flat 262144)
__global__ void p_text(const float* __restrict__ text,
                       unsigned short* __restrict__ eb) {
  int idx = blockIdx.x * 256 + threadIdx.x;
  eb[idx] = f2bf(text[idx]);
}

// P_img2: image read ONCE -> imgbp [bm][d][224] AND imgbp2 [bm][224][512]
__global__ void p_img2(const float* __restrict__ image,
                       unsigned short* __restrict__ imgbp,
                       unsigned short* __restrict__ imgbp2) {
  __shared__ float tile[32][33];
  int bm = blockIdx.x;
  int hw0 = blockIdx.y * 32;  // 7 tiles cover 224
  int d0 = blockIdx.z * 32;
  int tx = threadIdx.x, ty = threadIdx.y;
  const float* src = image + ((size_t)bm * DD + d0) * HWW + hw0;
#pragma unroll
  for (int r = 0; r < 32; r += 8) {
    int d = r + ty;
    float v = (hw0 + tx < HWW) ? src[(size_t)d * HWW + tx] : 0.f;
    tile[d][tx] = v;
    imgbp[((size_t)bm * DD + d0 + d) * HWP + hw0 + tx] = f2bf(v);
  }
  __syncthreads();
  unsigned short* dst = imgbp2 + ((size_t)bm * HWP + hw0) * DD + d0;
#pragma unroll
  for (int r = 0; r < 32; r += 8) {
    int hwo = r + ty;
    dst[(size_t)hwo * DD + tx] = f2bf(tile[tx][hwo]);
  }
}

// K1: per (ck, i): sim for all 8 j x 64 t vs 32 v-rows via MFMA.
// smem (32KB) holds XOR-swizzled v-tile during MFMA, then is reused as the
// attnR-chunk transpose buffer. attnR chunk-major [pair][ck][t][32].
__global__ void __launch_bounds__(256) k1_mfma(
    const unsigned short* __restrict__ eb,      // [8*64][512]
    const unsigned short* __restrict__ imgbp2,  // [bm][224][512]
    unsigned short* __restrict__ attnR,         // [pair][252][64][32]
    float* __restrict__ wpartg, float* __restrict__ apartg) {
  int ck = blockIdx.x;  // 0..251
  int i = blockIdx.y;   // 0..7
  int mi = ck / 7;
  int hwb = (ck - mi * 7) * 32;  // 0..192 step 32
  int bm = i * MM + mi;
  int tid = threadIdx.x;
  int w = tid >> 6, l = tid & 63;
  int g = l >> 4, c = l & 15;

  __shared__ unsigned short smem[16384];  // 32KB: swizzled vsb, then trb

  // stage: 32 v-rows x 512 d; 16B-unit XOR swizzle (unit ^ (row&7))
  const unsigned short* vsrc = imgbp2 + ((size_t)bm * HWP + hwb) * DD;
#pragma unroll
  for (int k = 0; k < 8; ++k) {
    int r = (tid >> 6) + k * 4;
    int u = tid & 63;
    *(s8v*)&smem[r * 512 + ((u ^ (r & 7)) << 3)] =
        *(const s8v*)(vsrc + (size_t)r * DD + (u << 3));
  }
  __syncthreads();

  f4v acc[8][2];  // [q (tAll-tile w*8+q)][nt]
#pragma unroll
  for (int q = 0; q < 8; ++q)
#pragma unroll
    for (int nt = 0; nt < 2; ++nt) acc[q][nt] = (f4v){0.f, 0.f, 0.f, 0.f};

  for (int ks = 0; ks < 16; ++ks) {
    int d0 = ks * 32;
    int u = 4 * ks + g;
    s8v Bf0 = *(const s8v*)&smem[c * 512 + ((u ^ (c & 7)) << 3)];
    s8v Bf1 = *(const s8v*)&smem[(16 + c) * 512 + ((u ^ ((16 + c) & 7)) << 3)];
#pragma unroll
    for (int q = 0; q < 8; ++q) {
      s8v Af = *(const s8v*)(eb + ((size_t)((w * 8 + q) * 16 + c)) * DD + d0 +
                             g * 8);
      acc[q][0] = __builtin_amdgcn_mfma_f32_16x16x32_bf16(Af, Bf0, acc[q][0], 0, 0, 0);
      acc[q][1] = __builtin_amdgcn_mfma_f32_16x16x32_bf16(Af, Bf1, acc[q][1], 0, 0, 0);
    }
  }

  // softmax over t per (jj, nt): reduce over q-subset+r regs, then g-lanes
  float rz[2][2];
#pragma unroll
  for (int jj = 0; jj < 2; ++jj)
#pragma unroll
    for (int nt = 0; nt < 2; ++nt) {
      float mx = -3e38f;
#pragma unroll
      for (int qq = 0; qq < 4; ++qq)
#pragma unroll
        for (int r = 0; r < 4; ++r) mx = fmaxf(mx, acc[jj * 4 + qq][nt][r]);
      mx = fmaxf(mx, __shfl_xor(mx, 16, 64));
      mx = fmaxf(mx, __shfl_xor(mx, 32, 64));
      float z = 0.f;
#pragma unroll
      for (int qq = 0; qq < 4; ++qq)
#pragma unroll
        for (int r = 0; r < 4; ++r) {
          float p = expf(acc[jj * 4 + qq][nt][r] - mx);
          acc[jj * 4 + qq][nt][r] = p;
          z += p;
        }
      z += __shfl_xor(z, 16, 64);
      z += __shfl_xor(z, 32, 64);
      rz[jj][nt] = 1.f / z;
    }

  __syncthreads();  // all vsb reads done; smem becomes trb

  // a4 = exp(4*ns) = exp(ns)^4; dump to trb; accumulate column sums
#pragma unroll
  for (int q = 0; q < 8; ++q) {
    int jj = q >> 2;
#pragma unroll
    for (int r = 0; r < 4; ++r) {
      float wp = 0.f, ap = 0.f;
#pragma unroll
      for (int nt = 0; nt < 2; ++nt) {
        float ns = acc[q][nt][r] * rz[jj][nt];
        float w1 = expf(ns);
        float a2 = w1 * w1;
        float a4 = a2 * a2;
        bool valid = (hwb + nt * 16 + c) < HWW;
        float a4m = valid ? a4 : 0.f;
        smem[((w * 8 + q) * 16 + g * 4 + r) * 32 + nt * 16 + c] = f2bf(a4m);
        wp += valid ? w1 : 0.f;
        ap += a4m;
      }
#pragma unroll
      for (int off = 1; off < 16; off <<= 1) {
        wp += __shfl_xor(wp, off, 64);
        ap += __shfl_xor(ap, off, 64);
      }
      if (c == 0) {
        int t = (q & 3) * 16 + g * 4 + r;
        size_t pidx = ((size_t)(i * 8 + 2 * w + jj) * NCK + ck) * 64 + t;
        wpartg[pidx] = wp;
        apartg[pidx] = ap;
      }
    }
  }
  __syncthreads();
  // linear coalesced copy trb -> attnR (8 pairs x 4KB)
#pragma unroll
  for (int j = 0; j < 8; ++j) {
    unsigned short* dst =
        attnR + ((size_t)(i * 8 + j) * NCK + ck) * 2048 + tid * 8;
    *(s8v*)dst = *(const s8v*)&smem[j * 2048 + tid * 8];
  }
}

// K_redbeta: Abuf[pair][t] = sum_ck apart; beta[t][m] directly (k4 folded)
__global__ void __launch_bounds__(256) k_redbeta(
    const float* __restrict__ wpartg, const float* __restrict__ apartg,
    float* __restrict__ beta, float* __restrict__ Abuf) {
  int pair = blockIdx.x;
  int tid = threadIdx.x;
  int t = tid & 63, part = tid >> 6;
  float s = 0.f;
  for (int ck = part; ck < NCK; ck += 4)
    s += apartg[((size_t)pair * NCK + ck) * 64 + t];
  __shared__ float ab[4][64];
  ab[part][t] = s;
  __syncthreads();
  if (tid < 64)
    Abuf[pair * 64 + tid] = ab[0][tid] + ab[1][tid] + ab[2][tid] + ab[3][tid];
  __shared__ float sl[TT * MM];
  for (int idx = tid; idx < TT * MM; idx += 256) {
    int tt = idx / MM, m = idx - (idx / MM) * MM;
    float ss = 0.f;
#pragma unroll
    for (int cc = 0; cc < 7; ++cc)
      ss += wpartg[((size_t)pair * NCK + m * 7 + cc) * 64 + tt];
    sl[idx] = ss;
  }
  __syncthreads();
  __shared__ float ls[MM];
  if (tid < MM) {
    float a = 0.f;
    for (int tq = 0; tq < TT; ++tq) a += sl[tq * MM + tid];
    ls[tid] = 1.f / a;
  }
  __syncthreads();
  for (int idx = tid; idx < TT * MM; idx += 256)
    beta[(size_t)pair * TT * MM + idx] = sl[idx] * ls[idx % MM];
}

// K2: vt_part[kslab][pair][t][d] = sum_{n in slab} a4[t][n] * v[n][d] via MFMA
__global__ void __launch_bounds__(256) k2_mfma(
    const unsigned short* __restrict__ attnR,
    const unsigned short* __restrict__ imgbp, float* __restrict__ vt_part) {
  int dh = blockIdx.x;     // 0..1 (d-half of 256)
  int kslab = blockIdx.y;  // 0..1 (4032 n each)
  int pair = blockIdx.z;
  int i = pair >> 3;
  int tid = threadIdx.x;
  int w = tid >> 6, l = tid & 63;
  int g = l >> 4, c = l & 15;
  int d0b = dh * 256;

  __shared__ unsigned short asb[TT][40];   // 5.1KB
  __shared__ unsigned short bsb[256][40];  // 20.5KB

  f4v acc[4][4];  // [tt][dd]
#pragma unroll
  for (int tt = 0; tt < 4; ++tt)
#pragma unroll
    for (int dd = 0; dd < 4; ++dd) acc[tt][dd] = (f4v){0.f, 0.f, 0.f, 0.f};

  for (int ks = 0; ks < 126; ++ks) {
    int ckg = kslab * 126 + ks;
    int n0 = ckg * 32;
    int mi = n0 / HWP, hw0 = n0 - mi * HWP;
    const unsigned short* bbase =
        imgbp + ((size_t)(i * MM + mi) * DD + d0b) * HWP + hw0;
    __syncthreads();
    {  // stage A: chunk-major attnR -> fully coalesced 4KB
      const unsigned short* ach = attnR + ((size_t)pair * NCK + ckg) * 2048;
      int t = tid >> 2, qq = tid & 3;
      *(s8v*)&asb[t][qq * 8] = *(const s8v*)(ach + tid * 8);
    }
#pragma unroll
    for (int u = 0; u < 4; ++u) {  // stage B: 256 d-rows x 32 n
      int idx = tid + u * 256;
      int d = idx >> 2, qq = idx & 3;
      *(s8v*)&bsb[d][qq * 8] = *(const s8v*)(bbase + (size_t)d * HWP + qq * 8);
    }
    __syncthreads();
    s8v Af[4];
#pragma unroll
    for (int tt = 0; tt < 4; ++tt)
      Af[tt] = *(const s8v*)&asb[tt * 16 + c][g * 8];
#pragma unroll
    for (int dd = 0; dd < 4; ++dd) {
      s8v Bf = *(const s8v*)&bsb[(w * 4 + dd) * 16 + c][g * 8];
#pragma unroll
      for (int tt = 0; tt < 4; ++tt)
        acc[tt][dd] = __builtin_amdgcn_mfma_f32_16x16x32_bf16(Af[tt], Bf,
                                                              acc[tt][dd], 0, 0, 0);
    }
  }
  float* op = vt_part + ((size_t)kslab * NPAIR + pair) * TT * DD;
#pragma unroll
  for (int tt = 0; tt < 4; ++tt)
#pragma unroll
    for (int dd = 0; dd < 4; ++dd)
#pragma unroll
      for (int r = 0; r < 4; ++r) {
        int t = tt * 16 + g * 4 + r;
        int d = d0b + (w * 4 + dd) * 16 + c;
        op[(size_t)t * DD + d] = acc[tt][dd][r];
      }
}

// K3 (+k2b folded): diag[t] = dot((slab0+slab1)/A, e[t]); r_qd via LSE
__global__ void __launch_bounds__(256) k3_rqd(
    const float* __restrict__ vt_part, const float* __restrict__ Abuf,
    const float* __restrict__ text, float* __restrict__ r_qd) {
  int pair = blockIdx.x;
  int j = pair & 7;
  const size_t slab = (size_t)NPAIR * TT * DD;
  int lane = threadIdx.x & 63, wid = threadIdx.x >> 6;
  __shared__ float dg[TT];
  for (int tt = 0; tt < 16; ++tt) {
    int t = wid * 16 + tt;
    const float* vt = vt_part + ((size_t)pair * TT + t) * DD;
    const float* e = text + ((size_t)j * TT + t) * DD;
    float a = 0.f;
#pragma unroll
    for (int k = 0; k < 8; ++k) {
      int d = k * 64 + lane;
      a = fmaf(vt[d] + vt[slab + d], e[d], a);
    }
    a = bflySum(a);
    if (lane == 0) dg[t] = a / Abuf[pair * 64 + t];
  }
  __syncthreads();
  if (threadIdx.x < TT) {
    float v = dg[threadIdx.x] * G2c;
    float mxv = bflyMax(v);
    float zz = bflySum(expf(v - mxv));
    if (threadIdx.x == 0) r_qd[pair] = (mxv + logf(zz)) / G2c;
  }
}

// K5: e_prime[m][d] = sum_t e[t][d]*beta[t][m]; ep_norm
__global__ void __launch_bounds__(256) k5_eprime(
    const float* __restrict__ text, const float* __restrict__ beta,
    float* __restrict__ e_prime, float* __restrict__ ep_norm) {
  int m = blockIdx.x, pair = blockIdx.y;
  int j = pair & 7;
  int d = threadIdx.x * 2;
  float a0 = 0.f, a1 = 0.f;
  const float* bt = beta + (size_t)pair * TT * MM + m;
  const float* e = text + (size_t)j * TT * DD + d;
  for (int t = 0; t < TT; ++t) {
    float b = bt[t * MM];
    float2 ev = *(const float2*)(e + (size_t)t * DD);
    a0 = fmaf(ev.x, b, a0);
    a1 = fmaf(ev.y, b, a1);
  }
  *(float2*)(e_prime + ((size_t)pair * MM + m) * DD + d) = make_float2(a0, a1);
  __shared__ float buf[4];
  float nr = bflySum(a0 * a0 + a1 * a1);
  int lane = threadIdx.x & 63, wid = threadIdx.x >> 6;
  if (lane == 0) buf[wid] = nr;
  __syncthreads();
  if (threadIdx.x == 0)
    ep_norm[pair * MM + m] = sqrtf(buf[0] + buf[1] + buf[2] + buf[3]);
}

// K6: per (m, i) block computes all 8 j per v-row read (8x less traffic)
__global__ void __launch_bounds__(256) k6_ref(
    const unsigned short* __restrict__ imgbp2,
    const float* __restrict__ e_prime, const float* __restrict__ ep_norm,
    float* __restrict__ refb) {
  int m = blockIdx.x, i = blockIdx.y;
  int bm = i * MM + m;
  int tid = threadIdx.x, w = tid >> 6, l = tid & 63;
  float epr[8][8];
  float ren[8];
#pragma unroll
  for (int j = 0; j < 8; ++j) {
    int pair = i * 8 + j;
    const float* ep = e_prime + ((size_t)pair * MM + m) * DD + l * 8;
    float4 e0 = *(const float4*)ep;
    float4 e1 = *(const float4*)(ep + 4);
    epr[j][0] = e0.x; epr[j][1] = e0.y; epr[j][2] = e0.z; epr[j][3] = e0.w;
    epr[j][4] = e1.x; epr[j][5] = e1.y; epr[j][6] = e1.z; epr[j][7] = e1.w;
    ren[j] = 1.f / ep_norm[pair * MM + m];
  }
  float accv[8];
#pragma unroll
  for (int j = 0; j < 8; ++j) accv[j] = 0.f;
  for (int k = 0; k < 49; ++k) {
    int hw = w + 4 * k;  // 4 waves x 49 = 196
    s8v v8 = *(const s8v*)(imgbp2 + ((size_t)bm * HWP + hw) * DD + l * 8);
    float vv[8];
    float rn = 0.f;
#pragma unroll
    for (int e = 0; e < 8; ++e) {
      vv[e] = bf2f((unsigned short)v8[e]);
      rn = fmaf(vv[e], vv[e], rn);
    }
    rn = bflySum(rn);
    float rs = rsqrtf(rn);
#pragma unroll
    for (int j = 0; j < 8; ++j) {
      float ve = 0.f;
#pragma unroll
      for (int e = 0; e < 8; ++e) ve = fmaf(vv[e], epr[j][e], ve);
      ve = bflySum(ve);
      accv[j] += ve * rs * ren[j];
    }
  }
  __shared__ float buf[4][8];
  if (l == 0) {
#pragma unroll
    for (int j = 0; j < 8; ++j) buf[w][j] = accv[j];
  }
  __syncthreads();
  if (tid < 8) {
    float s = buf[0][tid] + buf[1][tid] + buf[2][tid] + buf[3][tid];
    refb[(i * 8 + tid) * MM + m] = s * (1.0f / HWW);
  }
}

// K8a: per-b beta-regularizer partial
__global__ void __launch_bounds__(256) k8a(const float* __restrict__ beta,
                                           float* __restrict__ sregs) {
  int b = blockIdx.x;
  __shared__ float bb[TT * MM];
  __shared__ float buf[4];
  int tid = threadIdx.x;
  size_t base = (size_t)(b * BB + b) * TT * MM;
  for (int idx = tid; idx < TT * MM; idx += 256) bb[idx] = beta[base + idx];
  __syncthreads();
  float val = 0.f;
  for (int k = 0; k < 16; ++k) {
    int idx = tid + k * 256;
    int t = idx >> 6, s2 = idx & 63;
    if (t != s2) {
      float dot = 0.f;
      for (int mi = 0; mi < MM; ++mi)
        dot = fmaf(bb[t * MM + mi], bb[s2 * MM + mi], dot);
      val += dot * dot;
    }
  }
  val = bflySum(val);
  int lane = tid & 63, wid = tid >> 6;
  if (lane == 0) buf[wid] = val;
  __syncthreads();
  if (tid == 0) sregs[b] = sqrtf(fmaxf(buf[0] + buf[1] + buf[2] + buf[3], 0.f));
}

// K8b (+k7 folded): Sb then final scalar loss
__global__ void k8_final(const float* __restrict__ refb,
                         const float* __restrict__ r_qd,
                         const float* __restrict__ sregs,
                         const int* __restrict__ spinds,
                         float* __restrict__ out) {
  __shared__ float Sl[NPAIR];
  int tid = threadIdx.x;
  if (tid < NPAIR) {
    const float* r = refb + tid * MM;
    float mx = -1e30f;
    for (int mi = 0; mi < MM; ++mi) mx = fmaxf(mx, r[mi]);
    float z = 0.f;
    for (int mi = 0; mi < MM; ++mi) z += expf(r[mi] - mx);
    Sl[tid] = r_qd[tid] + (mx + logf(z)) / G2c;
  }
  __syncthreads();
  if (tid == 0) {
    float sreg = 0.f;
    for (int b = 0; b < BB; ++b) sreg += sregs[b];
    float l1 = 0.f, l2 = 0.f;
    for (int i = 0; i < BB; ++i) {
      float num = G3c * expf(Sl[i * BB + i]);
      float pdq = 0.f, pqd = 0.f;
      for (int k = 0; k < 5; ++k) {
        int kk = spinds[i * 5 + k];
        pdq += G3c * expf(Sl[i * BB + kk]);
        pqd += G3c * expf(Sl[kk * BB + i]);
      }
      l1 += num / pdq;
      l2 += num / pqd;
    }
    out[0] = -(l1 / BB) - (l2 / BB) + sreg / (float)(BB * TT * MM);
  }
}

extern "C" void kernel_launch(void* const* d_in, const int* in_sizes, int n_in,
                              void* d_out, int out_size, void* d_ws,
                              size_t ws_size, hipStream_t stream) {
  const float* image = (const float*)d_in[0];
  const float* text = (const float*)d_in[1];
  const int* spinds = (const int*)d_in[3];
  float* out = (float*)d_out;

  float* ws = (float*)d_ws;
  size_t off = 0;
  unsigned short* attnR = (unsigned short*)(ws + off);
  off += (size_t)NPAIR * NCK * 2048 / 2;  // 66MB bf16
  unsigned short* imgbp = (unsigned short*)(ws + off);
  off += (size_t)BB * MM * DD * HWP / 2;
  unsigned short* imgbp2 = (unsigned short*)(ws + off);
  off += (size_t)BB * MM * HWP * DD / 2;
  float* vt_part = ws + off; off += (size_t)2 * NPAIR * TT * DD;  // 4.2M
  unsigned short* eb = (unsigned short*)(ws + off);
  off += (size_t)BB * TT * DD / 2;
  float* wpartg = ws + off;  off += (size_t)NPAIR * NCK * 64;
  float* apartg = ws + off;  off += (size_t)NPAIR * NCK * 64;
  float* Abuf = ws + off;    off += (size_t)NPAIR * TT;
  float* beta = ws + off;    off += (size_t)NPAIR * TT * MM;
  float* e_prime = ws + off; off += (size_t)NPAIR * MM * DD;
  float* ep_norm = ws + off; off += (size_t)NPAIR * MM;
  float* refb = ws + off;    off += (size_t)NPAIR * MM;
  float* r_qd = ws + off;    off += (size_t)NPAIR;
  float* sregs = ws + off;   off += (size_t)BB;

  p_text<<<1024, 256, 0, stream>>>(text, eb);
  p_img2<<<dim3(BB * MM, 7, 16), dim3(32, 8), 0, stream>>>(image, imgbp,
                                                           imgbp2);
  k1_mfma<<<dim3(NCK, BB), 256, 0, stream>>>(eb, imgbp2, attnR, wpartg, apartg);
  k_redbeta<<<NPAIR, 256, 0, stream>>>(wpartg, apartg, beta, Abuf);
  k2_mfma<<<dim3(2, 2, NPAIR), 256, 0, stream>>>(attnR, imgbp, vt_part);
  k3_rqd<<<NPAIR, 256, 0, stream>>>(vt_part, Abuf, text, r_qd);
  k5_eprime<<<dim3(MM, NPAIR), 256, 0, stream>>>(text, beta, e_prime, ep_norm);
  k6_ref<<<dim3(MM, BB), 256, 0, stream>>>(imgbp2, e_prime, ep_norm, refb);
  k8a<<<BB, 256, 0, stream>>>(beta, sregs);
  k8_final<<<1, 64, 0, stream>>>(refb, r_qd, sregs, spinds, out);
}